// Round 1
// baseline (326.867 us; speedup 1.0000x reference)
//
#include <hip/hip_runtime.h>

// DeBERTa disentangled attention, MI355X fp16-MFMA implementation.
// B=16 S=512 D=768 H=12 HD=64 L=512.  All MFMA f16 16x16x32, fp32 accum.
// idx = q-k+512 (clip is a no-op for S=512,L=512) -> diagonal-band GEMMs.

typedef _Float16 f16;
typedef f16 f16x4 __attribute__((ext_vector_type(4)));
typedef f16 f16x8 __attribute__((ext_vector_type(8)));
typedef float f32x4 __attribute__((ext_vector_type(4)));

#define D_ 768

// swizzled index for [rows][64] f16 LDS tiles (128B rows): XOR 8-elem granule
__device__ __forceinline__ int swz(int r, int c) { return r * 64 + (c ^ ((r & 7) << 3)); }
// swizzled index for [rows][128] f16 band buffers (256B rows)
__device__ __forceinline__ int swzb(int r, int c) { return r * 128 + (c ^ ((r & 7) << 3)); }

__device__ __forceinline__ f32x4 mfma16(f16x8 a, f16x8 b, f32x4 c) {
  return __builtin_amdgcn_mfma_f32_16x16x32_f16(a, b, c, 0, 0, 0);
}

// ---------------- W transpose + cvt:  Wt[n][k] = (f16) W[k][n] ----------------
__global__ __launch_bounds__(256) void wtk(const float* __restrict__ W, f16* __restrict__ Wt) {
  __shared__ float t[32][33];
  int tx = threadIdx.x, ty = threadIdx.y;           // 32 x 8
  int k0 = blockIdx.x * 32, n0 = blockIdx.y * 32;
  for (int i = ty; i < 32; i += 8) t[i][tx] = W[(k0 + i) * D_ + n0 + tx];
  __syncthreads();
  for (int i = ty; i < 32; i += 8) Wt[(n0 + i) * D_ + k0 + tx] = (f16)t[tx][i];
}

// ---------------- projection GEMM: out16 = f16(A @ W + bias), permuted store --
// A [M x 768] fp32, Wt [768n x 768k] f16.  BM=BN=128, BK=64, 256 thr, 4 waves.
// MODE 0: m=b*512+s, n=h*64+hd -> out[((b*12+h)*512+s)*64+hd]   (QKV)
// MODE 1: n=h*64+hd            -> out[((h)*1024+m)*64+hd]       (pos tables)
template <int MODE>
__global__ __launch_bounds__(256) void gemm_proj(const float* __restrict__ A,
                                                 const f16* __restrict__ Wt,
                                                 const float* __restrict__ bias,
                                                 f16* __restrict__ out) {
  __shared__ f16 As[128 * 64];
  __shared__ f16 Bs[128 * 64];
  int tid = threadIdx.x, lane = tid & 63, wid = tid >> 6;
  int g4 = lane >> 4, l16 = lane & 15;
  int m0 = blockIdx.x * 128, n0 = blockIdx.y * 128;
  int wr = wid >> 1, wc = wid & 1;
  f32x4 acc[4][4] = {};

  for (int kb = 0; kb < 12; kb++) {
    int k0 = kb * 64;
    __syncthreads();
    // stage A tile (128 x 64) fp32 -> f16, coalesced
#pragma unroll
    for (int i = 0; i < 8; i++) {
      int s = tid + i * 256;
      int r = s >> 4, c = (s & 15) * 4;
      const float4 x = *(const float4*)(A + (m0 + r) * D_ + k0 + c);
      f16x4 hv; hv[0] = (f16)x.x; hv[1] = (f16)x.y; hv[2] = (f16)x.z; hv[3] = (f16)x.w;
      *(f16x4*)&As[swz(r, c)] = hv;
    }
    // stage B tile (128 n-rows x 64 k) from pre-transposed Wt (f16), coalesced
#pragma unroll
    for (int i = 0; i < 4; i++) {
      int s = tid + i * 256;
      int r = s >> 3, c = (s & 7) * 8;
      *(f16x8*)&Bs[swz(r, c)] = *(const f16x8*)(Wt + (n0 + r) * D_ + k0 + c);
    }
    __syncthreads();
#pragma unroll
    for (int ks = 0; ks < 2; ks++) {
      f16x8 af[4], bf[4];
#pragma unroll
      for (int mi = 0; mi < 4; mi++) af[mi] = *(const f16x8*)&As[swz(wr * 64 + mi * 16 + l16, ks * 32 + g4 * 8)];
#pragma unroll
      for (int ni = 0; ni < 4; ni++) bf[ni] = *(const f16x8*)&Bs[swz(wc * 64 + ni * 16 + l16, ks * 32 + g4 * 8)];
#pragma unroll
      for (int mi = 0; mi < 4; mi++)
#pragma unroll
        for (int ni = 0; ni < 4; ni++) acc[mi][ni] = mfma16(af[mi], bf[ni], acc[mi][ni]);
    }
  }
  // epilogue: +bias, cvt f16, permuted store
#pragma unroll
  for (int mi = 0; mi < 4; mi++)
#pragma unroll
    for (int ni = 0; ni < 4; ni++)
#pragma unroll
      for (int j = 0; j < 4; j++) {
        int m = m0 + wr * 64 + mi * 16 + g4 * 4 + j;
        int n = n0 + wc * 64 + ni * 16 + l16;
        float v = acc[mi][ni][j] + bias[n];
        int h = n >> 6, hd = n & 63;
        int idx;
        if (MODE == 0) {
          int b = m >> 9, s = m & 511;
          idx = (((b * 12 + h) * 512) + s) * 64 + hd;
        } else {
          idx = ((h * 1024) + m) * 64 + hd;
        }
        out[idx] = (f16)v;
      }
}

// ---------------- fused disentangled attention ----------------
// grid (8 qblocks, 12 h, 16 b), 256 threads (4 waves).  QBLK=KBLK=64.
// scores = (QK^T + gather(Q.posk^T band) + gather(K.posq^T band)) / sqrt(192)
__global__ __launch_bounds__(256) void attn(const f16* __restrict__ Qh, const f16* __restrict__ Kh,
                                            const f16* __restrict__ Vh, const f16* __restrict__ posk,
                                            const f16* __restrict__ posq, float* __restrict__ out) {
  __shared__ f16 Qs[64 * 64];
  __shared__ f16 Ks[64 * 64];
  __shared__ f16 Vts[64 * 64];   // transposed: [d][k]
  __shared__ f16 Ps[64 * 64];
  __shared__ f16 bcp[64 * 128];  // c2p band: [q][ploc]
  __shared__ f16 bpc[64 * 128];  // p2c band: [k][ploc]

  int tid = threadIdx.x, lane = tid & 63, wid = tid >> 6;
  int g4 = lane >> 4, l16 = lane & 15;
  int q0 = blockIdx.x * 64;
  int h = blockIdx.y;
  int b = blockIdx.z;
  const f16* Qg = Qh + (b * 12 + h) * 512 * 64;
  const f16* Kg = Kh + (b * 12 + h) * 512 * 64;
  const f16* Vg = Vh + (b * 12 + h) * 512 * 64;
  const f16* PKg = posk + h * 1024 * 64;
  const f16* PQg = posq + h * 1024 * 64;

  // stage Q (once)
#pragma unroll
  for (int i = 0; i < 2; i++) {
    int s = tid + i * 256;
    int r = s >> 3, c = (s & 7) * 8;
    *(f16x8*)&Qs[swz(r, c)] = *(const f16x8*)(Qg + (q0 + r) * 64 + c);
  }

  float mx[4], lsum[4];
  f32x4 ctx[4] = {};
#pragma unroll
  for (int j = 0; j < 4; j++) { mx[j] = -1e30f; lsum[j] = 0.f; }
  const float inv_scale = 0.07216878364870323f;  // 1/sqrt(192)
  int a32 = (wid >> 1) * 32, b64 = (wid & 1) * 64;

  for (int kb = 0; kb < 8; kb++) {
    int k0 = kb * 64;
    int pbase = q0 - k0 + 449;  // band rows pbase..pbase+126 used; +127 padded
    __syncthreads();            // B0: prev iter reads done before restage
    // stage K
#pragma unroll
    for (int i = 0; i < 2; i++) {
      int s = tid + i * 256;
      int r = s >> 3, c = (s & 7) * 8;
      *(f16x8*)&Ks[swz(r, c)] = *(const f16x8*)(Kg + (k0 + r) * 64 + c);
    }
    // stage V transposed: Vts[d][k] = V[k0+k][d]
#pragma unroll
    for (int i = 0; i < 2; i++) {
      int d0 = wid * 16 + i * 8;
      f16x8 v = *(const f16x8*)(Vg + (k0 + lane) * 64 + d0);
#pragma unroll
      for (int w = 0; w < 8; w++) Vts[swz(d0 + w, lane)] = v[w];
    }
    __syncthreads();  // B1

    // ---- c2c: wave strip 16q x 64k ----
    f32x4 accs[4] = {};
#pragma unroll
    for (int ks = 0; ks < 2; ks++) {
      f16x8 aq = *(const f16x8*)&Qs[swz(wid * 16 + l16, ks * 32 + g4 * 8)];
#pragma unroll
      for (int ni = 0; ni < 4; ni++) {
        f16x8 bk_ = *(const f16x8*)&Ks[swz(ni * 16 + l16, ks * 32 + g4 * 8)];
        accs[ni] = mfma16(aq, bk_, accs[ni]);
      }
    }
    // ---- c2p band: [64q x 128p], wave does 32q x 64p; B-frags straight from L2 ----
    {
      f32x4 a2[2][4] = {};
#pragma unroll
      for (int ks = 0; ks < 2; ks++) {
        f16x8 am0 = *(const f16x8*)&Qs[swz(a32 + l16, ks * 32 + g4 * 8)];
        f16x8 am1 = *(const f16x8*)&Qs[swz(a32 + 16 + l16, ks * 32 + g4 * 8)];
#pragma unroll
        for (int ni = 0; ni < 4; ni++) {
          int prow = pbase + b64 + ni * 16 + l16;
          prow = prow > 1023 ? 1023 : prow;
          f16x8 bp = *(const f16x8*)(PKg + prow * 64 + ks * 32 + g4 * 8);
          a2[0][ni] = mfma16(am0, bp, a2[0][ni]);
          a2[1][ni] = mfma16(am1, bp, a2[1][ni]);
        }
      }
#pragma unroll
      for (int mi = 0; mi < 2; mi++)
#pragma unroll
        for (int ni = 0; ni < 4; ni++)
#pragma unroll
          for (int j = 0; j < 4; j++)
            bcp[swzb(a32 + mi * 16 + g4 * 4 + j, b64 + ni * 16 + l16)] = (f16)a2[mi][ni][j];
    }
    // ---- p2c band: [64k x 128p], rows are keys ----
    {
      f32x4 a2[2][4] = {};
#pragma unroll
      for (int ks = 0; ks < 2; ks++) {
        f16x8 am0 = *(const f16x8*)&Ks[swz(a32 + l16, ks * 32 + g4 * 8)];
        f16x8 am1 = *(const f16x8*)&Ks[swz(a32 + 16 + l16, ks * 32 + g4 * 8)];
#pragma unroll
        for (int ni = 0; ni < 4; ni++) {
          int prow = pbase + b64 + ni * 16 + l16;
          prow = prow > 1023 ? 1023 : prow;
          f16x8 bp = *(const f16x8*)(PQg + prow * 64 + ks * 32 + g4 * 8);
          a2[0][ni] = mfma16(am0, bp, a2[0][ni]);
          a2[1][ni] = mfma16(am1, bp, a2[1][ni]);
        }
      }
#pragma unroll
      for (int mi = 0; mi < 2; mi++)
#pragma unroll
        for (int ni = 0; ni < 4; ni++)
#pragma unroll
          for (int j = 0; j < 4; j++)
            bpc[swzb(a32 + mi * 16 + g4 * 4 + j, b64 + ni * 16 + l16)] = (f16)a2[mi][ni][j];
    }
    __syncthreads();  // B2

    // ---- gather + online softmax ----
    float pv[4][4];
    float rowmax[4];
#pragma unroll
    for (int j = 0; j < 4; j++) rowmax[j] = -1e30f;
    int qb = wid * 16 + g4 * 4;
#pragma unroll
    for (int ni = 0; ni < 4; ni++) {
      int ki = ni * 16 + l16;
#pragma unroll
      for (int j = 0; j < 4; j++) {
        int q = qb + j;
        int ploc = q - ki + 63;  // in [0,126]
        float sc = (accs[ni][j] + (float)bcp[swzb(q, ploc)] + (float)bpc[swzb(ki, ploc)]) * inv_scale;
        pv[ni][j] = sc;
        rowmax[j] = fmaxf(rowmax[j], sc);
      }
    }
#pragma unroll
    for (int j = 0; j < 4; j++) {
      float m = rowmax[j];
#pragma unroll
      for (int t = 1; t < 16; t <<= 1) m = fmaxf(m, __shfl_xor(m, t, 64));
      float mnew = fmaxf(mx[j], m);
      float corr = __expf(mx[j] - mnew);
      mx[j] = mnew;
      lsum[j] *= corr;
#pragma unroll
      for (int nd = 0; nd < 4; nd++) ctx[nd][j] *= corr;
      float rs = 0.f;
#pragma unroll
      for (int ni = 0; ni < 4; ni++) {
        float p = __expf(pv[ni][j] - mnew);
        rs += p;
        Ps[swz(qb + j, ni * 16 + l16)] = (f16)p;
      }
#pragma unroll
      for (int t = 1; t < 16; t <<= 1) rs += __shfl_xor(rs, t, 64);
      lsum[j] += rs;
    }
    __syncthreads();  // B3

    // ---- PV: ctx[16q x 64d] += P[16q x 64k] * V[64k x 64d] ----
#pragma unroll
    for (int ks = 0; ks < 2; ks++) {
      f16x8 ap = *(const f16x8*)&Ps[swz(wid * 16 + l16, ks * 32 + g4 * 8)];
#pragma unroll
      for (int nd = 0; nd < 4; nd++) {
        f16x8 bv = *(const f16x8*)&Vts[swz(nd * 16 + l16, ks * 32 + g4 * 8)];
        ctx[nd] = mfma16(ap, bv, ctx[nd]);
      }
    }
  }
  // epilogue: out[b, q, h*64+d] = ctx / l
#pragma unroll
  for (int nd = 0; nd < 4; nd++)
#pragma unroll
    for (int j = 0; j < 4; j++) {
      int q = q0 + wid * 16 + g4 * 4 + j;
      int d = nd * 16 + l16;
      out[(b * 512 + q) * 768 + h * 64 + d] = ctx[nd][j] / lsum[j];
    }
}

extern "C" void kernel_launch(void* const* d_in, const int* in_sizes, int n_in,
                              void* d_out, int out_size, void* d_ws, size_t ws_size,
                              hipStream_t stream) {
  const float* q = (const float*)d_in[0];
  const float* k = (const float*)d_in[1];
  const float* v = (const float*)d_in[2];
  const float* rel = (const float*)d_in[3];
  const float* Wq = (const float*)d_in[4];
  const float* bq = (const float*)d_in[5];
  const float* Wk = (const float*)d_in[6];
  const float* bk = (const float*)d_in[7];
  const float* Wv = (const float*)d_in[8];
  const float* bv = (const float*)d_in[9];
  // d_in[10] = relative_pos: provably arange-difference; index computed analytically.
  float* out = (float*)d_out;

  f16* ws = (f16*)d_ws;  // ~44.4 MB used
  f16* Wtq = ws;
  f16* Wtk = Wtq + 589824;
  f16* Wtv = Wtk + 589824;
  f16* Qh = Wtv + 589824;
  f16* Kh = Qh + 6291456;
  f16* Vh = Kh + 6291456;
  f16* pk = Vh + 6291456;
  f16* pq = pk + 786432;

  dim3 tb(32, 8);
  wtk<<<dim3(24, 24), tb, 0, stream>>>(Wq, Wtq);
  wtk<<<dim3(24, 24), tb, 0, stream>>>(Wk, Wtk);
  wtk<<<dim3(24, 24), tb, 0, stream>>>(Wv, Wtv);
  gemm_proj<0><<<dim3(64, 6), 256, 0, stream>>>(q, Wtq, bq, Qh);
  gemm_proj<0><<<dim3(64, 6), 256, 0, stream>>>(k, Wtk, bk, Kh);
  gemm_proj<0><<<dim3(64, 6), 256, 0, stream>>>(v, Wtv, bv, Vh);
  gemm_proj<1><<<dim3(8, 6), 256, 0, stream>>>(rel, Wtk, bk, pk);
  gemm_proj<1><<<dim3(8, 6), 256, 0, stream>>>(rel, Wtq, bq, pq);
  attn<<<dim3(8, 12, 16), 256, 0, stream>>>(Qh, Kh, Vh, pk, pq, out);
}

// Round 3
// 326.547 us; speedup vs baseline: 1.0010x; 1.0010x over previous
//
#include <hip/hip_runtime.h>

// DeBERTa disentangled attention, MI355X fp16-MFMA implementation. R2b:
// transposed-score attn (lane owns a q-row), vectorized band writes, p2c
// write-side scatter, in-wave P round-trip (no B3), V pre-transposed.
// (R2 compile fix: cvt_pkrtz returns __fp16-based vector, wrap in pack4.)

typedef _Float16 f16;
typedef f16 f16x4 __attribute__((ext_vector_type(4)));
typedef f16 f16x8 __attribute__((ext_vector_type(8)));
typedef __fp16 fp16x2 __attribute__((ext_vector_type(2)));
typedef float f32x4 __attribute__((ext_vector_type(4)));

#define D_ 768

// swizzled index for [rows][64] f16 LDS tiles (128B rows): XOR 8-elem granule
__device__ __forceinline__ int swz(int r, int c) { return r * 64 + (c ^ ((r & 7) << 3)); }
// swizzled index for [rows][128] f16 band buffers (256B rows)
__device__ __forceinline__ int swzb(int r, int c) { return r * 128 + (c ^ ((r & 7) << 3)); }

__device__ __forceinline__ f32x4 mfma16(f16x8 a, f16x8 b, f32x4 c) {
  return __builtin_amdgcn_mfma_f32_16x16x32_f16(a, b, c, 0, 0, 0);
}

__device__ __forceinline__ f16x4 pack4(float a, float b, float c, float d) {
  fp16x2 lo = __builtin_amdgcn_cvt_pkrtz(a, b);
  fp16x2 hi = __builtin_amdgcn_cvt_pkrtz(c, d);
  f16x4 r;
  r[0] = (f16)lo[0]; r[1] = (f16)lo[1]; r[2] = (f16)hi[0]; r[3] = (f16)hi[1];
  return r;
}

// ---------------- W transpose + cvt:  Wt[n][k] = (f16) W[k][n] ----------------
__global__ __launch_bounds__(256) void wtk(const float* __restrict__ W, f16* __restrict__ Wt) {
  __shared__ float t[32][33];
  int tx = threadIdx.x, ty = threadIdx.y;  // 32 x 8
  int k0 = blockIdx.x * 32, n0 = blockIdx.y * 32;
  for (int i = ty; i < 32; i += 8) t[i][tx] = W[(k0 + i) * D_ + n0 + tx];
  __syncthreads();
  for (int i = ty; i < 32; i += 8) Wt[(n0 + i) * D_ + k0 + tx] = (f16)t[tx][i];
}

// ---------------- projection GEMM: out16 = f16(A @ W + bias), permuted store --
// MODE 0: out[((b*12+h)*512+s)*64+hd]      (Q,K: [b,h,s,hd])
// MODE 1: out[(h*1024+m)*64+hd]            (pos tables: [h,p,hd])
// MODE 2: out[((b*12+h)*64+hd)*512+s]      (V transposed: [b,h,hd,s])
template <int MODE>
__global__ __launch_bounds__(256) void gemm_proj(const float* __restrict__ A,
                                                 const f16* __restrict__ Wt,
                                                 const float* __restrict__ bias,
                                                 f16* __restrict__ out) {
  __shared__ f16 As[128 * 64];
  __shared__ f16 Bs[128 * 64];
  int tid = threadIdx.x, lane = tid & 63, wid = tid >> 6;
  int g4 = lane >> 4, l16 = lane & 15;
  int m0 = blockIdx.x * 128, n0 = blockIdx.y * 128;
  int wr = wid >> 1, wc = wid & 1;
  f32x4 acc[4][4] = {};

  for (int kb = 0; kb < 12; kb++) {
    int k0 = kb * 64;
    __syncthreads();
#pragma unroll
    for (int i = 0; i < 8; i++) {
      int s = tid + i * 256;
      int r = s >> 4, c = (s & 15) * 4;
      const float4 x = *(const float4*)(A + (m0 + r) * D_ + k0 + c);
      f16x4 hv; hv[0] = (f16)x.x; hv[1] = (f16)x.y; hv[2] = (f16)x.z; hv[3] = (f16)x.w;
      *(f16x4*)&As[swz(r, c)] = hv;
    }
#pragma unroll
    for (int i = 0; i < 4; i++) {
      int s = tid + i * 256;
      int r = s >> 3, c = (s & 7) * 8;
      *(f16x8*)&Bs[swz(r, c)] = *(const f16x8*)(Wt + (n0 + r) * D_ + k0 + c);
    }
    __syncthreads();
#pragma unroll
    for (int ks = 0; ks < 2; ks++) {
      f16x8 af[4], bf[4];
#pragma unroll
      for (int mi = 0; mi < 4; mi++) af[mi] = *(const f16x8*)&As[swz(wr * 64 + mi * 16 + l16, ks * 32 + g4 * 8)];
#pragma unroll
      for (int ni = 0; ni < 4; ni++) bf[ni] = *(const f16x8*)&Bs[swz(wc * 64 + ni * 16 + l16, ks * 32 + g4 * 8)];
#pragma unroll
      for (int mi = 0; mi < 4; mi++)
#pragma unroll
        for (int ni = 0; ni < 4; ni++) acc[mi][ni] = mfma16(af[mi], bf[ni], acc[mi][ni]);
    }
  }
#pragma unroll
  for (int mi = 0; mi < 4; mi++)
#pragma unroll
    for (int ni = 0; ni < 4; ni++) {
      int mb = m0 + wr * 64 + mi * 16 + g4 * 4;  // j=0 row
      int n = n0 + wc * 64 + ni * 16 + l16;
      int h = n >> 6, hd = n & 63;
      if (MODE == 2) {
        int b = mb >> 9, s = mb & 511;
        f16x4 hv;
#pragma unroll
        for (int j = 0; j < 4; j++) hv[j] = (f16)(acc[mi][ni][j] + bias[n]);
        *(f16x4*)&out[(((b * 12 + h) * 64) + hd) * 512 + s] = hv;
      } else {
#pragma unroll
        for (int j = 0; j < 4; j++) {
          int m = mb + j;
          float v = acc[mi][ni][j] + bias[n];
          int idx;
          if (MODE == 0) {
            int b = m >> 9, s = m & 511;
            idx = (((b * 12 + h) * 512) + s) * 64 + hd;
          } else {
            idx = ((h * 1024) + m) * 64 + hd;
          }
          out[idx] = (f16)v;
        }
      }
    }
}

// ---------------- fused disentangled attention (transposed-score layout) -----
// grid (8 qblocks, 12 h, 16 b), 256 threads (4 waves).  QBLK=KBLK=64.
// Lane owns q-row qrow = wid*16+l16; scores S^T[k][q] via mfma(K,Q).
__global__ __launch_bounds__(256) void attn(const f16* __restrict__ Qh, const f16* __restrict__ Kh,
                                            const f16* __restrict__ VhT, const f16* __restrict__ posk,
                                            const f16* __restrict__ posq, float* __restrict__ out) {
  __shared__ f16 Qs[64 * 64];
  __shared__ f16 Ks[64 * 64];
  __shared__ f16 Vts[64 * 64];   // [d][k]
  __shared__ f16 bcp[64 * 128];  // c2p band: [q][ploc]
  __shared__ f16 bs2[64 * 64];   // p2c scattered [q][k]; reused as P[q][k] after gather

  int tid = threadIdx.x, lane = tid & 63, wid = tid >> 6;
  int g4 = lane >> 4, l16 = lane & 15;
  int q0 = blockIdx.x * 64;
  int h = blockIdx.y, b = blockIdx.z;
  const f16* Qg = Qh + (b * 12 + h) * 512 * 64;
  const f16* Kg = Kh + (b * 12 + h) * 512 * 64;
  const f16* Vg = VhT + (b * 12 + h) * 64 * 512;  // [d][s]
  const f16* PKg = posk + h * 1024 * 64;
  const f16* PQg = posq + h * 1024 * 64;

  // stage Q once
#pragma unroll
  for (int i = 0; i < 2; i++) {
    int s = tid + i * 256;
    int r = s >> 3, c = (s & 7) * 8;
    *(f16x8*)&Qs[swz(r, c)] = *(const f16x8*)(Qg + (q0 + r) * 64 + c);
  }

  int qrow = wid * 16 + l16;  // this lane's local q
  float mx = -1e30f, lsum = 0.f;
  f32x4 ctx[4] = {};  // ctx^T: d = mi*16+g4*4+j, q = qrow
  const float inv_scale = 0.07216878364870323f;  // 1/sqrt(192)

  for (int kb = 0; kb < 8; kb++) {
    int k0 = kb * 64;
    int pbase = q0 - k0 + 449;
    __syncthreads();  // B0: prev-iter reads done before restage
    // stage K [k][d]
#pragma unroll
    for (int i = 0; i < 2; i++) {
      int s = tid + i * 256;
      int r = s >> 3, c = (s & 7) * 8;
      *(f16x8*)&Ks[swz(r, c)] = *(const f16x8*)(Kg + (k0 + r) * 64 + c);
    }
    // stage V^T [d][k] (vector loads from pre-transposed global V)
#pragma unroll
    for (int i = 0; i < 2; i++) {
      int s = tid + i * 256;
      int r = s >> 3, c = (s & 7) * 8;
      *(f16x8*)&Vts[swz(r, c)] = *(const f16x8*)(Vg + r * 512 + k0 + c);
    }
    __syncthreads();  // B1

    f16x8 qf[2], kfw[2], kf[2][4];
#pragma unroll
    for (int ks = 0; ks < 2; ks++) {
      qf[ks] = *(const f16x8*)&Qs[swz(qrow, ks * 32 + g4 * 8)];
      kfw[ks] = *(const f16x8*)&Ks[swz(qrow, ks * 32 + g4 * 8)];
#pragma unroll
      for (int ni = 0; ni < 4; ni++)
        kf[ks][ni] = *(const f16x8*)&Ks[swz(ni * 16 + l16, ks * 32 + g4 * 8)];
    }
    // ---- c2c^T: sc[ni] rows k=ni*16+g4*4+j, col q=qrow ----
    f32x4 sc[4] = {};
#pragma unroll
    for (int ks = 0; ks < 2; ks++)
#pragma unroll
      for (int ni = 0; ni < 4; ni++) sc[ni] = mfma16(kf[ks][ni], qf[ks], sc[ni]);

    // ---- c2p band: C[ploc][q] = pk_band x Q -> bcp[qrow][ploc] vectorized ----
#pragma unroll
    for (int mi = 0; mi < 8; mi++) {
      f32x4 a2 = {};
#pragma unroll
      for (int ks = 0; ks < 2; ks++) {
        int prow = pbase + mi * 16 + l16;
        prow = prow > 1023 ? 1023 : prow;
        f16x8 bp = *(const f16x8*)(PKg + prow * 64 + ks * 32 + g4 * 8);
        a2 = mfma16(bp, qf[ks], a2);
      }
      *(f16x4*)&bcp[swzb(qrow, mi * 16 + g4 * 4)] = pack4(a2[0], a2[1], a2[2], a2[3]);
    }
    // ---- p2c band: C[k][ploc] = K x pq_band -> scatter bs2[q][k] ----
#pragma unroll
    for (int nb = 0; nb < 8; nb++) {
      f32x4 a2 = {};
#pragma unroll
      for (int ks = 0; ks < 2; ks++) {
        int prow = pbase + nb * 16 + l16;
        prow = prow > 1023 ? 1023 : prow;
        f16x8 bq_ = *(const f16x8*)(PQg + prow * 64 + ks * 32 + g4 * 8);
        a2 = mfma16(kfw[ks], bq_, a2);
      }
#pragma unroll
      for (int j = 0; j < 4; j++) {
        int kk = wid * 16 + g4 * 4 + j;
        int qq = nb * 16 + l16 + kk - 63;
        if (qq >= 0 && qq < 64) bs2[swz(qq, kk)] = (f16)a2[j];
      }
    }
    __syncthreads();  // B2

    // ---- gather + online softmax (per-lane, q = qrow) ----
    float pr[4][4];
    float mt = -1e30f;
#pragma unroll
    for (int ni = 0; ni < 4; ni++) {
      int kb4 = ni * 16 + g4 * 4;
      f16x4 pc = *(const f16x4*)&bs2[swz(qrow, kb4)];
#pragma unroll
      for (int j = 0; j < 4; j++) {
        int ploc = qrow - (kb4 + j) + 63;  // in [0,126]
        float v = (sc[ni][j] + (float)bcp[swzb(qrow, ploc)] + (float)pc[j]) * inv_scale;
        pr[ni][j] = v;
        mt = fmaxf(mt, v);
      }
    }
    mt = fmaxf(mt, __shfl_xor(mt, 16, 64));
    mt = fmaxf(mt, __shfl_xor(mt, 32, 64));
    float mnew = fmaxf(mx, mt);
    float corr = __expf(mx - mnew);
    mx = mnew;
    lsum *= corr;
#pragma unroll
    for (int mi = 0; mi < 4; mi++) ctx[mi] *= corr;
    float rs = 0.f;
#pragma unroll
    for (int ni = 0; ni < 4; ni++) {
      float p0 = __expf(pr[ni][0] - mnew), p1 = __expf(pr[ni][1] - mnew);
      float p2 = __expf(pr[ni][2] - mnew), p3 = __expf(pr[ni][3] - mnew);
      rs += (p0 + p1) + (p2 + p3);
      *(f16x4*)&bs2[swz(qrow, ni * 16 + g4 * 4)] = pack4(p0, p1, p2, p3);  // own strip
    }
    rs += __shfl_xor(rs, 16, 64);
    rs += __shfl_xor(rs, 32, 64);
    lsum += rs;

    // ---- PV^T: ctx[d][q] += V^T[d][k] * P^T[k][q] (P read back intra-wave) ----
    f16x8 pa[2];
#pragma unroll
    for (int ks = 0; ks < 2; ks++) pa[ks] = *(const f16x8*)&bs2[swz(qrow, ks * 32 + g4 * 8)];
#pragma unroll
    for (int mi = 0; mi < 4; mi++)
#pragma unroll
      for (int ks = 0; ks < 2; ks++) {
        f16x8 vf = *(const f16x8*)&Vts[swz(mi * 16 + l16, ks * 32 + g4 * 8)];
        ctx[mi] = mfma16(vf, pa[ks], ctx[mi]);
      }
  }
  // epilogue: out[b, q, h*64+d], vectorized float4
  float inv_l = 1.0f / lsum;
#pragma unroll
  for (int mi = 0; mi < 4; mi++) {
    float4 o;
    o.x = ctx[mi][0] * inv_l;
    o.y = ctx[mi][1] * inv_l;
    o.z = ctx[mi][2] * inv_l;
    o.w = ctx[mi][3] * inv_l;
    *(float4*)&out[(b * 512 + q0 + qrow) * 768 + h * 64 + mi * 16 + g4 * 4] = o;
  }
}

extern "C" void kernel_launch(void* const* d_in, const int* in_sizes, int n_in,
                              void* d_out, int out_size, void* d_ws, size_t ws_size,
                              hipStream_t stream) {
  const float* q = (const float*)d_in[0];
  const float* k = (const float*)d_in[1];
  const float* v = (const float*)d_in[2];
  const float* rel = (const float*)d_in[3];
  const float* Wq = (const float*)d_in[4];
  const float* bq = (const float*)d_in[5];
  const float* Wk = (const float*)d_in[6];
  const float* bk = (const float*)d_in[7];
  const float* Wv = (const float*)d_in[8];
  const float* bv = (const float*)d_in[9];
  float* out = (float*)d_out;

  f16* ws = (f16*)d_ws;
  f16* Wtq = ws;
  f16* Wtk = Wtq + 589824;
  f16* Wtv = Wtk + 589824;
  f16* Qh = Wtv + 589824;
  f16* Kh = Qh + 6291456;
  f16* VhT = Kh + 6291456;
  f16* pk = VhT + 6291456;
  f16* pq = pk + 786432;

  dim3 tb(32, 8);
  wtk<<<dim3(24, 24), tb, 0, stream>>>(Wq, Wtq);
  wtk<<<dim3(24, 24), tb, 0, stream>>>(Wk, Wtk);
  wtk<<<dim3(24, 24), tb, 0, stream>>>(Wv, Wtv);
  gemm_proj<0><<<dim3(64, 6), 256, 0, stream>>>(q, Wtq, bq, Qh);
  gemm_proj<0><<<dim3(64, 6), 256, 0, stream>>>(k, Wtk, bk, Kh);
  gemm_proj<2><<<dim3(64, 6), 256, 0, stream>>>(v, Wtv, bv, VhT);
  gemm_proj<1><<<dim3(8, 6), 256, 0, stream>>>(rel, Wtk, bk, pk);
  gemm_proj<1><<<dim3(8, 6), 256, 0, stream>>>(rel, Wtq, bq, pq);
  attn<<<dim3(8, 12, 16), 256, 0, stream>>>(Qh, Kh, VhT, pk, pq, out);
}

// Round 4
// 231.394 us; speedup vs baseline: 1.4126x; 1.4112x over previous
//
#include <hip/hip_runtime.h>

// DeBERTa disentangled attention, MI355X fp16-MFMA. R4: latency attack.
// - Band tiles staged cooperatively into LDS (was: 4x-redundant global loads
//   feeding MFMAs directly -> serialized L2/L3 latency chains, 7% MfmaUtil).
// - T14 prefetch: next iter's 12 staging loads issued into regs right after
//   current LDS commit; written to LDS next iter (compute phase hides latency).
// - c2p AND p2c band outputs scattered by k into [q][k] buffers (single
//   writer/cell); softmax does aligned f16x4 vector reads only.
// - Q kept in registers (each lane only needs its own q-row).
// - Bijective XCD swizzle: 8 q-blocks sharing K/V/pos -> same XCD L2.

typedef _Float16 f16;
typedef f16 f16x4 __attribute__((ext_vector_type(4)));
typedef f16 f16x8 __attribute__((ext_vector_type(8)));
typedef __fp16 fp16x2 __attribute__((ext_vector_type(2)));
typedef float f32x4 __attribute__((ext_vector_type(4)));

#define D_ 768

__device__ __forceinline__ int swz(int r, int c) { return r * 64 + (c ^ ((r & 7) << 3)); }

__device__ __forceinline__ f32x4 mfma16(f16x8 a, f16x8 b, f32x4 c) {
  return __builtin_amdgcn_mfma_f32_16x16x32_f16(a, b, c, 0, 0, 0);
}

__device__ __forceinline__ f16x4 pack4(float a, float b, float c, float d) {
  fp16x2 lo = __builtin_amdgcn_cvt_pkrtz(a, b);
  fp16x2 hi = __builtin_amdgcn_cvt_pkrtz(c, d);
  f16x4 r;
  r[0] = (f16)lo[0]; r[1] = (f16)lo[1]; r[2] = (f16)hi[0]; r[3] = (f16)hi[1];
  return r;
}

// ---------------- W transpose + cvt:  Wt[n][k] = (f16) W[k][n] ----------------
__global__ __launch_bounds__(256) void wtk(const float* __restrict__ W, f16* __restrict__ Wt) {
  __shared__ float t[32][33];
  int tx = threadIdx.x, ty = threadIdx.y;  // 32 x 8
  int k0 = blockIdx.x * 32, n0 = blockIdx.y * 32;
  for (int i = ty; i < 32; i += 8) t[i][tx] = W[(k0 + i) * D_ + n0 + tx];
  __syncthreads();
  for (int i = ty; i < 32; i += 8) Wt[(n0 + i) * D_ + k0 + tx] = (f16)t[tx][i];
}

// ---------------- projection GEMM: out16 = f16(A @ W + bias), permuted store --
// MODE 0: out[((b*12+h)*512+s)*64+hd]      (Q,K: [b,h,s,hd])
// MODE 1: out[(h*1024+m)*64+hd]            (pos tables: [h,p,hd])
// MODE 2: out[((b*12+h)*64+hd)*512+s]      (V transposed: [b,h,hd,s])
template <int MODE>
__global__ __launch_bounds__(256) void gemm_proj(const float* __restrict__ A,
                                                 const f16* __restrict__ Wt,
                                                 const float* __restrict__ bias,
                                                 f16* __restrict__ out) {
  __shared__ f16 As[128 * 64];
  __shared__ f16 Bs[128 * 64];
  int tid = threadIdx.x, lane = tid & 63, wid = tid >> 6;
  int g4 = lane >> 4, l16 = lane & 15;
  int m0 = blockIdx.x * 128, n0 = blockIdx.y * 128;
  int wr = wid >> 1, wc = wid & 1;
  f32x4 acc[4][4] = {};

  for (int kb = 0; kb < 12; kb++) {
    int k0 = kb * 64;
    __syncthreads();
#pragma unroll
    for (int i = 0; i < 8; i++) {
      int s = tid + i * 256;
      int r = s >> 4, c = (s & 15) * 4;
      const float4 x = *(const float4*)(A + (m0 + r) * D_ + k0 + c);
      f16x4 hv; hv[0] = (f16)x.x; hv[1] = (f16)x.y; hv[2] = (f16)x.z; hv[3] = (f16)x.w;
      *(f16x4*)&As[swz(r, c)] = hv;
    }
#pragma unroll
    for (int i = 0; i < 4; i++) {
      int s = tid + i * 256;
      int r = s >> 3, c = (s & 7) * 8;
      *(f16x8*)&Bs[swz(r, c)] = *(const f16x8*)(Wt + (n0 + r) * D_ + k0 + c);
    }
    __syncthreads();
#pragma unroll
    for (int ks = 0; ks < 2; ks++) {
      f16x8 af[4], bf[4];
#pragma unroll
      for (int mi = 0; mi < 4; mi++) af[mi] = *(const f16x8*)&As[swz(wr * 64 + mi * 16 + l16, ks * 32 + g4 * 8)];
#pragma unroll
      for (int ni = 0; ni < 4; ni++) bf[ni] = *(const f16x8*)&Bs[swz(wc * 64 + ni * 16 + l16, ks * 32 + g4 * 8)];
#pragma unroll
      for (int mi = 0; mi < 4; mi++)
#pragma unroll
        for (int ni = 0; ni < 4; ni++) acc[mi][ni] = mfma16(af[mi], bf[ni], acc[mi][ni]);
    }
  }
#pragma unroll
  for (int mi = 0; mi < 4; mi++)
#pragma unroll
    for (int ni = 0; ni < 4; ni++) {
      int mb = m0 + wr * 64 + mi * 16 + g4 * 4;  // j=0 row
      int n = n0 + wc * 64 + ni * 16 + l16;
      int h = n >> 6, hd = n & 63;
      if (MODE == 2) {
        int b = mb >> 9, s = mb & 511;
        f16x4 hv;
#pragma unroll
        for (int j = 0; j < 4; j++) hv[j] = (f16)(acc[mi][ni][j] + bias[n]);
        *(f16x4*)&out[(((b * 12 + h) * 64) + hd) * 512 + s] = hv;
      } else {
#pragma unroll
        for (int j = 0; j < 4; j++) {
          int m = mb + j;
          float v = acc[mi][ni][j] + bias[n];
          int idx;
          if (MODE == 0) {
            int b = m >> 9, s = m & 511;
            idx = (((b * 12 + h) * 512) + s) * 64 + hd;
          } else {
            idx = ((h * 1024) + m) * 64 + hd;
          }
          out[idx] = (f16)v;
        }
      }
    }
}

// ---------------- fused disentangled attention ----------------
// flat grid 1536 blocks (XCD-swizzled), 256 threads (4 waves). QBLK=KBLK=64.
// Lane owns q-row qrow; scores S^T[k][q] via mfma(K,Q).
__global__ __launch_bounds__(256, 2) void attn(const f16* __restrict__ Qh, const f16* __restrict__ Kh,
                                               const f16* __restrict__ VhT, const f16* __restrict__ posk,
                                               const f16* __restrict__ posq, float* __restrict__ out) {
  __shared__ f16 Ks_[64 * 64];   // 8 KB  [k][d]
  __shared__ f16 Vts[64 * 64];   // 8 KB  [d][k]
  __shared__ f16 Bcp[128 * 64];  // 16 KB posk band rows [r][d]
  __shared__ f16 Bpq[128 * 64];  // 16 KB posq band rows [r][d]
  __shared__ f16 bsA[64 * 64];   // 8 KB  c2p gathered [q][k]; P[q][k] after softmax
  __shared__ f16 bs2[64 * 64];   // 8 KB  p2c gathered [q][k]

  int tid = threadIdx.x, lane = tid & 63, wid = tid >> 6;
  int g4 = lane >> 4, l16 = lane & 15;
  // bijective XCD swizzle (1536 % 8 == 0): 8 q-blocks of one (h,b) -> same XCD
  int flat = blockIdx.x;
  int work = (flat & 7) * 192 + (flat >> 3);
  int q0 = (work & 7) * 64;
  int hb = work >> 3;
  int h = hb % 12, b = hb / 12;

  const f16* Qg = Qh + (b * 12 + h) * 512 * 64;
  const f16* Kg = Kh + (b * 12 + h) * 512 * 64;
  const f16* Vg = VhT + (b * 12 + h) * 64 * 512;  // [d][s]
  const f16* PKg = posk + h * 1024 * 64;
  const f16* PQg = posq + h * 1024 * 64;

  int qrow = wid * 16 + l16;  // lane's local q
  // Q row in registers (lane only ever needs its own row)
  f16x8 qf[2];
#pragma unroll
  for (int ks = 0; ks < 2; ks++) qf[ks] = *(const f16x8*)(Qg + (q0 + qrow) * 64 + ks * 32 + g4 * 8);

  // prefetch registers
  f16x8 pfK[2], pfV[2], pfC[4], pfP[4];
  int sr = tid >> 3, sc8 = (tid & 7) * 8;  // staging row/col for i=0 slice (tid<512 pattern)

  auto issue = [&](int kb) {
    int k0 = kb * 64, pbase = q0 - k0 + 449;
#pragma unroll
    for (int i = 0; i < 2; i++) {
      int s = tid + i * 256, r = s >> 3, c = (s & 7) * 8;
      pfK[i] = *(const f16x8*)(Kg + (k0 + r) * 64 + c);
      pfV[i] = *(const f16x8*)(Vg + r * 512 + k0 + c);
    }
#pragma unroll
    for (int i = 0; i < 4; i++) {
      int s = tid + i * 256, r = s >> 3, c = (s & 7) * 8;
      int prow = pbase + r;
      prow = prow > 1023 ? 1023 : prow;
      pfC[i] = *(const f16x8*)(PKg + prow * 64 + c);
      pfP[i] = *(const f16x8*)(PQg + prow * 64 + c);
    }
  };
  auto commit = [&]() {
#pragma unroll
    for (int i = 0; i < 2; i++) {
      int s = tid + i * 256, r = s >> 3, c = (s & 7) * 8;
      *(f16x8*)&Ks_[swz(r, c)] = pfK[i];
      *(f16x8*)&Vts[swz(r, c)] = pfV[i];
    }
#pragma unroll
    for (int i = 0; i < 4; i++) {
      int s = tid + i * 256, r = s >> 3, c = (s & 7) * 8;
      *(f16x8*)&Bcp[swz(r, c)] = pfC[i];
      *(f16x8*)&Bpq[swz(r, c)] = pfP[i];
    }
  };

  float mx = -1e30f, lsum = 0.f;
  f32x4 ctx[4] = {};  // ctx^T: d = mi*16+g4*4+j, q = qrow
  const float inv_scale = 0.07216878364870323f;  // 1/sqrt(192)

  issue(0);
  for (int kb = 0; kb < 8; kb++) {
    commit();             // waits prefetch, writes LDS
    if (kb < 7) issue(kb + 1);  // next iter's loads fly during compute
    __syncthreads();      // S1: LDS ready

    // ---- fragment reads ----
    f16x8 kfw[2], kf[2][4];
#pragma unroll
    for (int ks = 0; ks < 2; ks++) {
      kfw[ks] = *(const f16x8*)&Ks_[swz(qrow, ks * 32 + g4 * 8)];
#pragma unroll
      for (int ni = 0; ni < 4; ni++)
        kf[ks][ni] = *(const f16x8*)&Ks_[swz(ni * 16 + l16, ks * 32 + g4 * 8)];
    }
    // ---- c2c^T: sc[ni] rows k=ni*16+g4*4+j, col q=qrow ----
    f32x4 sc[4] = {};
#pragma unroll
    for (int ks = 0; ks < 2; ks++)
#pragma unroll
      for (int ni = 0; ni < 4; ni++) sc[ni] = mfma16(kf[ks][ni], qf[ks], sc[ni]);

    // ---- c2p: C[ploc][q], A from LDS band; scatter by k into bsA[qrow][k] ----
#pragma unroll
    for (int mi = 0; mi < 8; mi++) {
      f32x4 a2 = {};
#pragma unroll
      for (int ks = 0; ks < 2; ks++) {
        f16x8 bp = *(const f16x8*)&Bcp[swz(mi * 16 + l16, ks * 32 + g4 * 8)];
        a2 = mfma16(bp, qf[ks], a2);
      }
#pragma unroll
      for (int j = 0; j < 4; j++) {
        int ploc = mi * 16 + g4 * 4 + j;
        int kk = qrow - ploc + 63;
        if (kk >= 0 && kk < 64) bsA[swz(qrow, kk)] = (f16)a2[j];
      }
    }
    // ---- p2c: C[k][ploc], B from LDS band; scatter into bs2[q][k] ----
#pragma unroll
    for (int nb = 0; nb < 8; nb++) {
      f32x4 a2 = {};
#pragma unroll
      for (int ks = 0; ks < 2; ks++) {
        f16x8 bq_ = *(const f16x8*)&Bpq[swz(nb * 16 + l16, ks * 32 + g4 * 8)];
        a2 = mfma16(kfw[ks], bq_, a2);
      }
#pragma unroll
      for (int j = 0; j < 4; j++) {
        int kk = wid * 16 + g4 * 4 + j;
        int qq = nb * 16 + l16 + kk - 63;
        if (qq >= 0 && qq < 64) bs2[swz(qq, kk)] = (f16)a2[j];
      }
    }
    __syncthreads();  // S2: scatters visible

    // ---- softmax: aligned vector reads only ----
    float pr[4][4];
    float mt = -1e30f;
    f16x4 pa4[4], pc4[4];
#pragma unroll
    for (int ni = 0; ni < 4; ni++) {
      int kb4 = ni * 16 + g4 * 4;
      pa4[ni] = *(const f16x4*)&bsA[swz(qrow, kb4)];
      pc4[ni] = *(const f16x4*)&bs2[swz(qrow, kb4)];
    }
#pragma unroll
    for (int ni = 0; ni < 4; ni++)
#pragma unroll
      for (int j = 0; j < 4; j++) {
        float v = (sc[ni][j] + (float)pa4[ni][j] + (float)pc4[ni][j]) * inv_scale;
        pr[ni][j] = v;
        mt = fmaxf(mt, v);
      }
    mt = fmaxf(mt, __shfl_xor(mt, 16, 64));
    mt = fmaxf(mt, __shfl_xor(mt, 32, 64));
    float mnew = fmaxf(mx, mt);
    float corr = __expf(mx - mnew);
    mx = mnew;
    lsum *= corr;
#pragma unroll
    for (int mi = 0; mi < 4; mi++) ctx[mi] *= corr;
    float rs = 0.f;
#pragma unroll
    for (int ni = 0; ni < 4; ni++) {
      float p0 = __expf(pr[ni][0] - mnew), p1 = __expf(pr[ni][1] - mnew);
      float p2 = __expf(pr[ni][2] - mnew), p3 = __expf(pr[ni][3] - mnew);
      rs += (p0 + p1) + (p2 + p3);
      *(f16x4*)&bsA[swz(qrow, ni * 16 + g4 * 4)] = pack4(p0, p1, p2, p3);  // P, own row
    }
    rs += __shfl_xor(rs, 16, 64);
    rs += __shfl_xor(rs, 32, 64);
    lsum += rs;

    // ---- PV^T: ctx[d][q] += V^T[d][k] * P^T[k][q] (P read intra-wave) ----
    f16x8 pa[2];
#pragma unroll
    for (int ks = 0; ks < 2; ks++) pa[ks] = *(const f16x8*)&bsA[swz(qrow, ks * 32 + g4 * 8)];
#pragma unroll
    for (int mi = 0; mi < 4; mi++)
#pragma unroll
      for (int ks = 0; ks < 2; ks++) {
        f16x8 vf = *(const f16x8*)&Vts[swz(mi * 16 + l16, ks * 32 + g4 * 8)];
        ctx[mi] = mfma16(vf, pa[ks], ctx[mi]);
      }
    __syncthreads();  // S3: all reads done before next commit
  }
  // epilogue: out[b, q, h*64+d], vectorized float4
  float inv_l = 1.0f / lsum;
#pragma unroll
  for (int mi = 0; mi < 4; mi++) {
    float4 o;
    o.x = ctx[mi][0] * inv_l;
    o.y = ctx[mi][1] * inv_l;
    o.z = ctx[mi][2] * inv_l;
    o.w = ctx[mi][3] * inv_l;
    *(float4*)&out[(b * 512 + q0 + qrow) * 768 + h * 64 + mi * 16 + g4 * 4] = o;
  }
}

extern "C" void kernel_launch(void* const* d_in, const int* in_sizes, int n_in,
                              void* d_out, int out_size, void* d_ws, size_t ws_size,
                              hipStream_t stream) {
  const float* q = (const float*)d_in[0];
  const float* k = (const float*)d_in[1];
  const float* v = (const float*)d_in[2];
  const float* rel = (const float*)d_in[3];
  const float* Wq = (const float*)d_in[4];
  const float* bq = (const float*)d_in[5];
  const float* Wk = (const float*)d_in[6];
  const float* bk = (const float*)d_in[7];
  const float* Wv = (const float*)d_in[8];
  const float* bv = (const float*)d_in[9];
  float* out = (float*)d_out;

  f16* ws = (f16*)d_ws;
  f16* Wtq = ws;
  f16* Wtk = Wtq + 589824;
  f16* Wtv = Wtk + 589824;
  f16* Qh = Wtv + 589824;
  f16* Kh = Qh + 6291456;
  f16* VhT = Kh + 6291456;
  f16* pk = VhT + 6291456;
  f16* pq = pk + 786432;

  dim3 tb(32, 8);
  wtk<<<dim3(24, 24), tb, 0, stream>>>(Wq, Wtq);
  wtk<<<dim3(24, 24), tb, 0, stream>>>(Wk, Wtk);
  wtk<<<dim3(24, 24), tb, 0, stream>>>(Wv, Wtv);
  gemm_proj<0><<<dim3(64, 6), 256, 0, stream>>>(q, Wtq, bq, Qh);
  gemm_proj<0><<<dim3(64, 6), 256, 0, stream>>>(k, Wtk, bk, Kh);
  gemm_proj<2><<<dim3(64, 6), 256, 0, stream>>>(v, Wtv, bv, VhT);
  gemm_proj<1><<<dim3(8, 6), 256, 0, stream>>>(rel, Wtk, bk, pk);
  gemm_proj<1><<<dim3(8, 6), 256, 0, stream>>>(rel, Wtq, bq, pq);
  attn<<<dim3(1536), 256, 0, stream>>>(Qh, Kh, VhT, pk, pq, out);
}

// Round 5
// 226.806 us; speedup vs baseline: 1.4412x; 1.0202x over previous
//
#include <hip/hip_runtime.h>

// DeBERTa disentangled attention, MI355X fp16-MFMA. R5:
// - 5-tile band windows per wave (valid parallelogram only): MFMA 48->36,
//   scatter issues 64->40 per lane-iter, band frag reads 32->20.
// - 2 barriers/iter (V-frags hoisted before S2; commit needs no 3rd barrier).
// - exp2-domain online softmax (log2e folded into scale).
// - s_setprio(1) around MFMA clusters.
// - gemm_proj: global_load_lds(16B) for B-tile with pre-swizzled source.

typedef _Float16 f16;
typedef f16 f16x4 __attribute__((ext_vector_type(4)));
typedef f16 f16x8 __attribute__((ext_vector_type(8)));
typedef __fp16 fp16x2 __attribute__((ext_vector_type(2)));
typedef float f32x4 __attribute__((ext_vector_type(4)));

#define D_ 768

__device__ __forceinline__ int swz(int r, int c) { return r * 64 + (c ^ ((r & 7) << 3)); }

__device__ __forceinline__ f32x4 mfma16(f16x8 a, f16x8 b, f32x4 c) {
  return __builtin_amdgcn_mfma_f32_16x16x32_f16(a, b, c, 0, 0, 0);
}

__device__ __forceinline__ f16x4 pack4(float a, float b, float c, float d) {
  fp16x2 lo = __builtin_amdgcn_cvt_pkrtz(a, b);
  fp16x2 hi = __builtin_amdgcn_cvt_pkrtz(c, d);
  f16x4 r;
  r[0] = (f16)lo[0]; r[1] = (f16)lo[1]; r[2] = (f16)hi[0]; r[3] = (f16)hi[1];
  return r;
}

__device__ __forceinline__ void gll16(const f16* g, f16* l) {
  __builtin_amdgcn_global_load_lds((const __attribute__((address_space(1))) void*)g,
                                   (__attribute__((address_space(3))) void*)l, 16, 0, 0);
}

// ---------------- W transpose + cvt:  Wt[n][k] = (f16) W[k][n] ----------------
__global__ __launch_bounds__(256) void wtk(const float* __restrict__ W, f16* __restrict__ Wt) {
  __shared__ float t[32][33];
  int tx = threadIdx.x, ty = threadIdx.y;  // 32 x 8
  int k0 = blockIdx.x * 32, n0 = blockIdx.y * 32;
  for (int i = ty; i < 32; i += 8) t[i][tx] = W[(k0 + i) * D_ + n0 + tx];
  __syncthreads();
  for (int i = ty; i < 32; i += 8) Wt[(n0 + i) * D_ + k0 + tx] = (f16)t[tx][i];
}

// ---------------- projection GEMM: out16 = f16(A @ W + bias), permuted store --
// MODE 0: out[((b*12+h)*512+s)*64+hd]      (Q,K: [b,h,s,hd])
// MODE 1: out[(h*1024+m)*64+hd]            (pos tables: [h,p,hd])
// MODE 2: out[((b*12+h)*64+hd)*512+s]      (V transposed: [b,h,hd,s])
template <int MODE>
__global__ __launch_bounds__(256) void gemm_proj(const float* __restrict__ A,
                                                 const f16* __restrict__ Wt,
                                                 const float* __restrict__ bias,
                                                 f16* __restrict__ out) {
  __shared__ f16 As[128 * 64];
  __shared__ f16 Bs[128 * 64];
  int tid = threadIdx.x, lane = tid & 63, wid = tid >> 6;
  int g4 = lane >> 4, l16 = lane & 15;
  int m0 = blockIdx.x * 128, n0 = blockIdx.y * 128;
  int wr = wid >> 1, wc = wid & 1;
  f32x4 acc[4][4] = {};

  for (int kb = 0; kb < 12; kb++) {
    int k0 = kb * 64;
    __syncthreads();
    // B tile via global_load_lds, source pre-swizzled (linear LDS dest)
#pragma unroll
    for (int i = 0; i < 4; i++) {
      int s = tid + i * 256;
      int r = s >> 3, c = (s & 7) * 8;
      int csw = c ^ ((r & 7) << 3);
      gll16(Wt + (n0 + r) * D_ + k0 + csw, &Bs[s * 8]);
    }
    // A tile (128 x 64) fp32 -> f16, reg path
#pragma unroll
    for (int i = 0; i < 8; i++) {
      int s = tid + i * 256;
      int r = s >> 4, c = (s & 15) * 4;
      const float4 x = *(const float4*)(A + (m0 + r) * D_ + k0 + c);
      f16x4 hv; hv[0] = (f16)x.x; hv[1] = (f16)x.y; hv[2] = (f16)x.z; hv[3] = (f16)x.w;
      *(f16x4*)&As[swz(r, c)] = hv;
    }
    __syncthreads();
#pragma unroll
    for (int ks = 0; ks < 2; ks++) {
      f16x8 af[4], bf[4];
#pragma unroll
      for (int mi = 0; mi < 4; mi++) af[mi] = *(const f16x8*)&As[swz(wr * 64 + mi * 16 + l16, ks * 32 + g4 * 8)];
#pragma unroll
      for (int ni = 0; ni < 4; ni++) bf[ni] = *(const f16x8*)&Bs[swz(wc * 64 + ni * 16 + l16, ks * 32 + g4 * 8)];
#pragma unroll
      for (int mi = 0; mi < 4; mi++)
#pragma unroll
        for (int ni = 0; ni < 4; ni++) acc[mi][ni] = mfma16(af[mi], bf[ni], acc[mi][ni]);
    }
  }
#pragma unroll
  for (int mi = 0; mi < 4; mi++)
#pragma unroll
    for (int ni = 0; ni < 4; ni++) {
      int mb = m0 + wr * 64 + mi * 16 + g4 * 4;  // j=0 row
      int n = n0 + wc * 64 + ni * 16 + l16;
      int h = n >> 6, hd = n & 63;
      if (MODE == 2) {
        int b = mb >> 9, s = mb & 511;
        f16x4 hv;
#pragma unroll
        for (int j = 0; j < 4; j++) hv[j] = (f16)(acc[mi][ni][j] + bias[n]);
        *(f16x4*)&out[(((b * 12 + h) * 64) + hd) * 512 + s] = hv;
      } else {
#pragma unroll
        for (int j = 0; j < 4; j++) {
          int m = mb + j;
          float v = acc[mi][ni][j] + bias[n];
          int idx;
          if (MODE == 0) {
            int b = m >> 9, s = m & 511;
            idx = (((b * 12 + h) * 512) + s) * 64 + hd;
          } else {
            idx = ((h * 1024) + m) * 64 + hd;
          }
          out[idx] = (f16)v;
        }
      }
    }
}

// ---------------- fused disentangled attention ----------------
// flat grid 1536 blocks (XCD-swizzled), 256 threads (4 waves). QBLK=KBLK=64.
// Lane owns q-row qrow; scores S^T[k][q] via mfma(K,Q).
__global__ __launch_bounds__(256, 2) void attn(const f16* __restrict__ Qh, const f16* __restrict__ Kh,
                                               const f16* __restrict__ VhT, const f16* __restrict__ posk,
                                               const f16* __restrict__ posq, float* __restrict__ out) {
  __shared__ f16 Ks_[64 * 64];   // 8 KB  [k][d]
  __shared__ f16 Vts[64 * 64];   // 8 KB  [d][k]
  __shared__ f16 Bcp[128 * 64];  // 16 KB posk band rows [r][d]
  __shared__ f16 Bpq[128 * 64];  // 16 KB posq band rows [r][d]
  __shared__ f16 bsA[64 * 64];   // 8 KB  c2p gathered [q][k]; P[q][k] after softmax
  __shared__ f16 bs2[64 * 64];   // 8 KB  p2c gathered [q][k]

  int tid = threadIdx.x, lane = tid & 63, wid = tid >> 6;
  int g4 = lane >> 4, l16 = lane & 15;
  // bijective XCD swizzle (1536 % 8 == 0): 8 q-blocks of one (h,b) -> same XCD
  int flat = blockIdx.x;
  int work = (flat & 7) * 192 + (flat >> 3);
  int q0 = (work & 7) * 64;
  int hb = work >> 3;
  int h = hb % 12, b = hb / 12;

  const f16* Qg = Qh + (b * 12 + h) * 512 * 64;
  const f16* Kg = Kh + (b * 12 + h) * 512 * 64;
  const f16* Vg = VhT + (b * 12 + h) * 64 * 512;  // [d][s]
  const f16* PKg = posk + h * 1024 * 64;
  const f16* PQg = posq + h * 1024 * 64;

  int qrow = wid * 16 + l16;  // lane's local q
  // Q row in registers (lane only ever needs its own row)
  f16x8 qf[2];
#pragma unroll
  for (int ks = 0; ks < 2; ks++) qf[ks] = *(const f16x8*)(Qg + (q0 + qrow) * 64 + ks * 32 + g4 * 8);

  // prefetch registers
  f16x8 pfK[2], pfV[2], pfC[4], pfP[4];

  auto issue = [&](int kb) {
    int k0 = kb * 64, pbase = q0 - k0 + 449;
#pragma unroll
    for (int i = 0; i < 2; i++) {
      int s = tid + i * 256, r = s >> 3, c = (s & 7) * 8;
      pfK[i] = *(const f16x8*)(Kg + (k0 + r) * 64 + c);
      pfV[i] = *(const f16x8*)(Vg + r * 512 + k0 + c);
    }
#pragma unroll
    for (int i = 0; i < 4; i++) {
      int s = tid + i * 256, r = s >> 3, c = (s & 7) * 8;
      int prow = pbase + r;
      prow = prow > 1023 ? 1023 : prow;
      pfC[i] = *(const f16x8*)(PKg + prow * 64 + c);
      pfP[i] = *(const f16x8*)(PQg + prow * 64 + c);
    }
  };
  auto commit = [&]() {
#pragma unroll
    for (int i = 0; i < 2; i++) {
      int s = tid + i * 256, r = s >> 3, c = (s & 7) * 8;
      *(f16x8*)&Ks_[swz(r, c)] = pfK[i];
      *(f16x8*)&Vts[swz(r, c)] = pfV[i];
    }
#pragma unroll
    for (int i = 0; i < 4; i++) {
      int s = tid + i * 256, r = s >> 3, c = (s & 7) * 8;
      *(f16x8*)&Bcp[swz(r, c)] = pfC[i];
      *(f16x8*)&Bpq[swz(r, c)] = pfP[i];
    }
  };

  float mx = -1e30f, lsum = 0.f;
  f32x4 ctx[4] = {};  // ctx^T: d = mi*16+g4*4+j, q = qrow
  // log2-domain scale: 1/sqrt(192) * log2(e)
  const float scale2 = 0.07216878364870323f * 1.4426950408889634f;

  issue(0);
  for (int kb = 0; kb < 8; kb++) {
    commit();                   // waits prefetch, writes LDS
    if (kb < 7) issue(kb + 1);  // next iter's loads fly during compute
    __syncthreads();            // S1: LDS ready (also: prev-iter bsA reads done)

    // ---- fragment reads (ALL staged-LDS reads happen before S2) ----
    f16x8 kfw[2], kf[2][4], vf[2][4];
#pragma unroll
    for (int ks = 0; ks < 2; ks++) {
      kfw[ks] = *(const f16x8*)&Ks_[swz(qrow, ks * 32 + g4 * 8)];
#pragma unroll
      for (int ni = 0; ni < 4; ni++) {
        kf[ks][ni] = *(const f16x8*)&Ks_[swz(ni * 16 + l16, ks * 32 + g4 * 8)];
        vf[ks][ni] = *(const f16x8*)&Vts[swz(ni * 16 + l16, ks * 32 + g4 * 8)];
      }
    }
    __builtin_amdgcn_s_setprio(1);
    // ---- c2c^T: sc[ni] rows k=ni*16+g4*4+j, col q=qrow ----
    f32x4 sc[4] = {};
#pragma unroll
    for (int ks = 0; ks < 2; ks++)
#pragma unroll
      for (int ni = 0; ni < 4; ni++) sc[ni] = mfma16(kf[ks][ni], qf[ks], sc[ni]);

    // ---- c2p: 5-tile window [wid, wid+4]; scatter into bsA[qrow][k] ----
#pragma unroll
    for (int t = 0; t < 5; t++) {
      int mi = wid + t;
      f32x4 a2 = {};
#pragma unroll
      for (int ks = 0; ks < 2; ks++) {
        f16x8 bp = *(const f16x8*)&Bcp[swz(mi * 16 + l16, ks * 32 + g4 * 8)];
        a2 = mfma16(bp, qf[ks], a2);
      }
      int plocb = mi * 16 + g4 * 4;
#pragma unroll
      for (int j = 0; j < 4; j++) {
        int kk = qrow - (plocb + j) + 63;
        if (kk >= 0 && kk < 64) bsA[swz(qrow, kk)] = (f16)a2[j];
      }
    }
    // ---- p2c: 5-tile window [3-wid, 7-wid]; scatter into bs2[q][k] ----
#pragma unroll
    for (int t = 0; t < 5; t++) {
      int nb = 3 - wid + t;
      f32x4 a2 = {};
#pragma unroll
      for (int ks = 0; ks < 2; ks++) {
        f16x8 bq_ = *(const f16x8*)&Bpq[swz(nb * 16 + l16, ks * 32 + g4 * 8)];
        a2 = mfma16(kfw[ks], bq_, a2);
      }
#pragma unroll
      for (int j = 0; j < 4; j++) {
        int kk = wid * 16 + g4 * 4 + j;
        int qq = nb * 16 + l16 + kk - 63;
        if (qq >= 0 && qq < 64) bs2[swz(qq, kk)] = (f16)a2[j];
      }
    }
    __builtin_amdgcn_s_setprio(0);
    __syncthreads();  // S2: scatters visible; staged LDS free for next commit

    // ---- softmax (log2 domain): aligned vector reads only ----
    float pr[4][4];
    float mt = -1e30f;
    f16x4 pa4[4], pc4[4];
#pragma unroll
    for (int ni = 0; ni < 4; ni++) {
      int kb4 = ni * 16 + g4 * 4;
      pa4[ni] = *(const f16x4*)&bsA[swz(qrow, kb4)];
      pc4[ni] = *(const f16x4*)&bs2[swz(qrow, kb4)];
    }
#pragma unroll
    for (int ni = 0; ni < 4; ni++)
#pragma unroll
      for (int j = 0; j < 4; j++) {
        float v = (sc[ni][j] + (float)pa4[ni][j] + (float)pc4[ni][j]) * scale2;
        pr[ni][j] = v;
        mt = fmaxf(mt, v);
      }
    mt = fmaxf(mt, __shfl_xor(mt, 16, 64));
    mt = fmaxf(mt, __shfl_xor(mt, 32, 64));
    float mnew = fmaxf(mx, mt);
    float corr = __builtin_amdgcn_exp2f(mx - mnew);
    mx = mnew;
    lsum *= corr;
#pragma unroll
    for (int mi = 0; mi < 4; mi++) ctx[mi] *= corr;
    float rs = 0.f;
#pragma unroll
    for (int ni = 0; ni < 4; ni++) {
      float p0 = __builtin_amdgcn_exp2f(pr[ni][0] - mnew);
      float p1 = __builtin_amdgcn_exp2f(pr[ni][1] - mnew);
      float p2 = __builtin_amdgcn_exp2f(pr[ni][2] - mnew);
      float p3 = __builtin_amdgcn_exp2f(pr[ni][3] - mnew);
      rs += (p0 + p1) + (p2 + p3);
      *(f16x4*)&bsA[swz(qrow, ni * 16 + g4 * 4)] = pack4(p0, p1, p2, p3);  // P, own row
    }
    rs += __shfl_xor(rs, 16, 64);
    rs += __shfl_xor(rs, 32, 64);
    lsum += rs;

    // ---- PV^T: ctx[d][q] += V^T[d][k] * P^T[k][q] (vf from regs) ----
    f16x8 pa[2];
#pragma unroll
    for (int ks = 0; ks < 2; ks++) pa[ks] = *(const f16x8*)&bsA[swz(qrow, ks * 32 + g4 * 8)];
    __builtin_amdgcn_s_setprio(1);
#pragma unroll
    for (int mi = 0; mi < 4; mi++)
#pragma unroll
      for (int ks = 0; ks < 2; ks++) ctx[mi] = mfma16(vf[ks][mi], pa[ks], ctx[mi]);
    __builtin_amdgcn_s_setprio(0);
    // no barrier: next S1 protects bsA/bs2; commit targets not read after S2
  }
  // epilogue: out[b, q, h*64+d], vectorized float4
  float inv_l = 1.0f / lsum;
#pragma unroll
  for (int mi = 0; mi < 4; mi++) {
    float4 o;
    o.x = ctx[mi][0] * inv_l;
    o.y = ctx[mi][1] * inv_l;
    o.z = ctx[mi][2] * inv_l;
    o.w = ctx[mi][3] * inv_l;
    *(float4*)&out[(b * 512 + q0 + qrow) * 768 + h * 64 + mi * 16 + g4 * 4] = o;
  }
}

extern "C" void kernel_launch(void* const* d_in, const int* in_sizes, int n_in,
                              void* d_out, int out_size, void* d_ws, size_t ws_size,
                              hipStream_t stream) {
  const float* q = (const float*)d_in[0];
  const float* k = (const float*)d_in[1];
  const float* v = (const float*)d_in[2];
  const float* rel = (const float*)d_in[3];
  const float* Wq = (const float*)d_in[4];
  const float* bq = (const float*)d_in[5];
  const float* Wk = (const float*)d_in[6];
  const float* bk = (const float*)d_in[7];
  const float* Wv = (const float*)d_in[8];
  const float* bv = (const float*)d_in[9];
  float* out = (float*)d_out;

  f16* ws = (f16*)d_ws;
  f16* Wtq = ws;
  f16* Wtk = Wtq + 589824;
  f16* Wtv = Wtk + 589824;
  f16* Qh = Wtv + 589824;
  f16* Kh = Qh + 6291456;
  f16* VhT = Kh + 6291456;
  f16* pk = VhT + 6291456;
  f16* pq = pk + 786432;

  dim3 tb(32, 8);
  wtk<<<dim3(24, 24), tb, 0, stream>>>(Wq, Wtq);
  wtk<<<dim3(24, 24), tb, 0, stream>>>(Wk, Wtk);
  wtk<<<dim3(24, 24), tb, 0, stream>>>(Wv, Wtv);
  gemm_proj<0><<<dim3(64, 6), 256, 0, stream>>>(q, Wtq, bq, Qh);
  gemm_proj<0><<<dim3(64, 6), 256, 0, stream>>>(k, Wtk, bk, Kh);
  gemm_proj<2><<<dim3(64, 6), 256, 0, stream>>>(v, Wtv, bv, VhT);
  gemm_proj<1><<<dim3(8, 6), 256, 0, stream>>>(rel, Wtk, bk, pk);
  gemm_proj<1><<<dim3(8, 6), 256, 0, stream>>>(rel, Wtq, bq, pq);
  attn<<<dim3(1536), 256, 0, stream>>>(Qh, Kh, VhT, pk, pq, out);
}

// Round 6
// 223.866 us; speedup vs baseline: 1.4601x; 1.0131x over previous
//
#include <hip/hip_runtime.h>

// DeBERTa disentangled attention, MI355X fp16-MFMA. R6:
// - Projections fused: one qkv GEMM launch (z=3), one pos launch (z=2),
//   one wtk launch (z=3); A-tile reg-prefetch + async gll16 B staging.
// - attn: K,V fragments direct-global prefetched into registers (staggered
//   single-buffer reissue); bands staged via async global_load_lds with
//   pre-swizzled source; LDS 48KB; defer-max softmax (THR=6, log2 domain)
//   with lane-partial lsum; no setprio.

typedef _Float16 f16;
typedef f16 f16x4 __attribute__((ext_vector_type(4)));
typedef f16 f16x8 __attribute__((ext_vector_type(8)));
typedef __fp16 fp16x2 __attribute__((ext_vector_type(2)));
typedef float f32x4 __attribute__((ext_vector_type(4)));

#define D_ 768

__device__ __forceinline__ int swz(int r, int c) { return r * 64 + (c ^ ((r & 7) << 3)); }

__device__ __forceinline__ f32x4 mfma16(f16x8 a, f16x8 b, f32x4 c) {
  return __builtin_amdgcn_mfma_f32_16x16x32_f16(a, b, c, 0, 0, 0);
}

__device__ __forceinline__ f16x4 pack4(float a, float b, float c, float d) {
  fp16x2 lo = __builtin_amdgcn_cvt_pkrtz(a, b);
  fp16x2 hi = __builtin_amdgcn_cvt_pkrtz(c, d);
  f16x4 r;
  r[0] = (f16)lo[0]; r[1] = (f16)lo[1]; r[2] = (f16)hi[0]; r[3] = (f16)hi[1];
  return r;
}

__device__ __forceinline__ void gll16(const f16* g, f16* l) {
  __builtin_amdgcn_global_load_lds((const __attribute__((address_space(1))) void*)g,
                                   (__attribute__((address_space(3))) void*)l, 16, 0, 0);
}

// ---------------- W transpose + cvt (z selects weight):  Wt[n][k] = (f16) W[k][n]
__global__ __launch_bounds__(256) void wtk3(const float* __restrict__ W0, const float* __restrict__ W1,
                                            const float* __restrict__ W2, f16* __restrict__ T0,
                                            f16* __restrict__ T1, f16* __restrict__ T2) {
  __shared__ float t[32][33];
  int z = blockIdx.z;
  const float* W = z == 0 ? W0 : z == 1 ? W1 : W2;
  f16* Wt = z == 0 ? T0 : z == 1 ? T1 : T2;
  int tx = threadIdx.x, ty = threadIdx.y;  // 32 x 8
  int k0 = blockIdx.x * 32, n0 = blockIdx.y * 32;
  for (int i = ty; i < 32; i += 8) t[i][tx] = W[(k0 + i) * D_ + n0 + tx];
  __syncthreads();
  for (int i = ty; i < 32; i += 8) Wt[(n0 + i) * D_ + k0 + tx] = (f16)t[tx][i];
}

// ---------------- fused projection GEMM: out16 = f16(A @ W + bias) ----------
// which==0 (grid z=3): z0 (q,Wtq,bq,Qh,m0) z1 (k,Wtk,bk,Kh,m0) z2 (v,Wtv,bv,VhT,m2)
// which==1 (grid z=2): z0 (rel,Wtk,bk,pk,m1) z1 (rel,Wtq,bq,pq,m1)
// mode 0: out[((b*12+h)*512+s)*64+hd]; mode 1: out[(h*1024+m)*64+hd];
// mode 2: out[((b*12+h)*64+hd)*512+s]
__global__ __launch_bounds__(256) void gemm_fused(
    const float* __restrict__ A0, const float* __restrict__ A1, const float* __restrict__ A2,
    const f16* __restrict__ W0, const f16* __restrict__ W1, const f16* __restrict__ W2,
    const float* __restrict__ b0, const float* __restrict__ b1, const float* __restrict__ b2,
    f16* __restrict__ o0, f16* __restrict__ o1, f16* __restrict__ o2, int which) {
  __shared__ f16 As[128 * 64];
  __shared__ f16 Bs[128 * 64];
  int z = blockIdx.z;
  const float* A; const f16* Wt; const float* bias; f16* out; int mode;
  if (which == 0) {
    A = z == 0 ? A0 : z == 1 ? A1 : A2;
    Wt = z == 0 ? W0 : z == 1 ? W1 : W2;
    bias = z == 0 ? b0 : z == 1 ? b1 : b2;
    out = z == 0 ? o0 : z == 1 ? o1 : o2;
    mode = z == 2 ? 2 : 0;
  } else {
    A = A0;
    Wt = z == 0 ? W1 : W0;
    bias = z == 0 ? b1 : b0;
    out = z == 0 ? o0 : o1;
    mode = 1;
  }
  int tid = threadIdx.x, lane = tid & 63, wid = tid >> 6;
  int g4 = lane >> 4, l16 = lane & 15;
  int m0 = blockIdx.x * 128, n0 = blockIdx.y * 128;
  int wr = wid >> 1, wc = wid & 1;
  f32x4 acc[4][4] = {};
  float4 pfA[8];

  auto issueA = [&](int k0) {
#pragma unroll
    for (int i = 0; i < 8; i++) {
      int s = tid + i * 256, r = s >> 4, c = (s & 15) * 4;
      pfA[i] = *(const float4*)(A + (m0 + r) * D_ + k0 + c);
    }
  };

  issueA(0);
  for (int kb = 0; kb < 12; kb++) {
    int k0 = kb * 64;
    __syncthreads();  // prev-iter LDS reads done
    // B tile async via global_load_lds, source pre-swizzled (linear LDS dest)
#pragma unroll
    for (int i = 0; i < 4; i++) {
      int s = tid + i * 256, r = s >> 3, c = (s & 7) * 8;
      int csw = c ^ ((r & 7) << 3);
      gll16(Wt + (n0 + r) * D_ + k0 + csw, &Bs[s * 8]);
    }
    // A tile commit from prefetch regs (fp32 -> f16)
#pragma unroll
    for (int i = 0; i < 8; i++) {
      int s = tid + i * 256, r = s >> 4, c = (s & 15) * 4;
      float4 x = pfA[i];
      f16x4 hv; hv[0] = (f16)x.x; hv[1] = (f16)x.y; hv[2] = (f16)x.z; hv[3] = (f16)x.w;
      *(f16x4*)&As[swz(r, c)] = hv;
    }
    if (kb < 11) issueA(k0 + 64);
    __syncthreads();  // drains gll + ds_writes
#pragma unroll
    for (int ks = 0; ks < 2; ks++) {
      f16x8 af[4], bf[4];
#pragma unroll
      for (int mi = 0; mi < 4; mi++) af[mi] = *(const f16x8*)&As[swz(wr * 64 + mi * 16 + l16, ks * 32 + g4 * 8)];
#pragma unroll
      for (int ni = 0; ni < 4; ni++) bf[ni] = *(const f16x8*)&Bs[swz(wc * 64 + ni * 16 + l16, ks * 32 + g4 * 8)];
#pragma unroll
      for (int mi = 0; mi < 4; mi++)
#pragma unroll
        for (int ni = 0; ni < 4; ni++) acc[mi][ni] = mfma16(af[mi], bf[ni], acc[mi][ni]);
    }
  }
#pragma unroll
  for (int mi = 0; mi < 4; mi++)
#pragma unroll
    for (int ni = 0; ni < 4; ni++) {
      int mb = m0 + wr * 64 + mi * 16 + g4 * 4;  // j=0 row
      int n = n0 + wc * 64 + ni * 16 + l16;
      int h = n >> 6, hd = n & 63;
      if (mode == 2) {
        int b = mb >> 9, s = mb & 511;
        f16x4 hv;
#pragma unroll
        for (int j = 0; j < 4; j++) hv[j] = (f16)(acc[mi][ni][j] + bias[n]);
        *(f16x4*)&out[(((b * 12 + h) * 64) + hd) * 512 + s] = hv;
      } else {
#pragma unroll
        for (int j = 0; j < 4; j++) {
          int m = mb + j;
          float v = acc[mi][ni][j] + bias[n];
          int idx;
          if (mode == 0) {
            int b = m >> 9, s = m & 511;
            idx = (((b * 12 + h) * 512) + s) * 64 + hd;
          } else {
            idx = ((h * 1024) + m) * 64 + hd;
          }
          out[idx] = (f16)v;
        }
      }
    }
}

// ---------------- fused disentangled attention ----------------
// flat grid 1536 blocks (XCD-swizzled), 256 threads (4 waves). QBLK=KBLK=64.
// Lane owns q-row qrow; scores S^T[k][q] via mfma(K,Q). K,V frags live in
// registers (direct global, prefetched); bands in LDS via gll16.
__global__ __launch_bounds__(256, 2) void attn(const f16* __restrict__ Qh, const f16* __restrict__ Kh,
                                               const f16* __restrict__ VhT, const f16* __restrict__ posk,
                                               const f16* __restrict__ posq, float* __restrict__ out) {
  __shared__ f16 Bcp[128 * 64];  // 16 KB posk band rows [r][d] (swizzled)
  __shared__ f16 Bpq[128 * 64];  // 16 KB posq band rows [r][d] (swizzled)
  __shared__ f16 bsA[64 * 64];   // 8 KB  c2p gathered [q][k]; P[q][k] after softmax
  __shared__ f16 bs2[64 * 64];   // 8 KB  p2c gathered [q][k]

  int tid = threadIdx.x, lane = tid & 63, wid = tid >> 6;
  int g4 = lane >> 4, l16 = lane & 15;
  // bijective XCD swizzle (1536 % 8 == 0)
  int flat = blockIdx.x;
  int work = (flat & 7) * 192 + (flat >> 3);
  int q0 = (work & 7) * 64;
  int hb = work >> 3;
  int h = hb % 12, b = hb / 12;

  const f16* Qg = Qh + (b * 12 + h) * 512 * 64;
  const f16* Kg = Kh + (b * 12 + h) * 512 * 64;
  const f16* Vg = VhT + (b * 12 + h) * 64 * 512;  // [d][s]
  const f16* PKg = posk + h * 1024 * 64;
  const f16* PQg = posq + h * 1024 * 64;

  int qrow = wid * 16 + l16;  // lane's local q
  f16x8 qf[2];
#pragma unroll
  for (int ks = 0; ks < 2; ks++) qf[ks] = *(const f16x8*)(Qg + (q0 + qrow) * 64 + ks * 32 + g4 * 8);

  // K/V fragment registers (direct global, single-buffer staggered reissue)
  f16x8 kfw[2], kf[2][4], vf[2][4];
  auto issueK = [&](int kb) {
    int k0 = kb * 64;
#pragma unroll
    for (int ks = 0; ks < 2; ks++) {
      kfw[ks] = *(const f16x8*)(Kg + (k0 + qrow) * 64 + ks * 32 + g4 * 8);
#pragma unroll
      for (int ni = 0; ni < 4; ni++)
        kf[ks][ni] = *(const f16x8*)(Kg + (k0 + ni * 16 + l16) * 64 + ks * 32 + g4 * 8);
    }
  };
  auto issueV = [&](int kb) {
    int k0 = kb * 64;
#pragma unroll
    for (int ks = 0; ks < 2; ks++)
#pragma unroll
      for (int ni = 0; ni < 4; ni++)
        vf[ks][ni] = *(const f16x8*)(Vg + (ni * 16 + l16) * 512 + k0 + ks * 32 + g4 * 8);
  };
  auto issueBands = [&](int kb) {
    int k0 = kb * 64, pbase = q0 - k0 + 449;
#pragma unroll
    for (int i = 0; i < 4; i++) {
      int s = tid + i * 256, r = s >> 3, c = (s & 7) * 8;
      int prow = pbase + r;
      prow = prow > 1023 ? 1023 : prow;
      int csw = c ^ ((r & 7) << 3);
      gll16(PKg + prow * 64 + csw, &Bcp[s * 8]);
      gll16(PQg + prow * 64 + csw, &Bpq[s * 8]);
    }
  };

  float mx = -1e30f, lpart = 0.f;
  f32x4 ctx[4] = {};  // ctx^T: d = mi*16+g4*4+j, q = qrow
  // log2-domain scale: 1/sqrt(192) * log2(e)
  const float scale2 = 0.07216878364870323f * 1.4426950408889634f;

  issueK(0);
  issueV(0);
  issueBands(0);
  for (int kb = 0; kb < 8; kb++) {
    __syncthreads();  // S1: bands in LDS (drain), prev softmax reads of bs2 done

    // ---- c2c^T: sc[ni] rows k=ni*16+g4*4+j, col q=qrow ----
    f32x4 sc[4] = {};
#pragma unroll
    for (int ks = 0; ks < 2; ks++)
#pragma unroll
      for (int ni = 0; ni < 4; ni++) sc[ni] = mfma16(kf[ks][ni], qf[ks], sc[ni]);

    // ---- c2p: 5-tile window [wid, wid+4]; scatter into bsA[qrow][k] ----
#pragma unroll
    for (int t = 0; t < 5; t++) {
      int mi = wid + t;
      f32x4 a2 = {};
#pragma unroll
      for (int ks = 0; ks < 2; ks++) {
        f16x8 bp = *(const f16x8*)&Bcp[swz(mi * 16 + l16, ks * 32 + g4 * 8)];
        a2 = mfma16(bp, qf[ks], a2);
      }
      int plocb = mi * 16 + g4 * 4;
#pragma unroll
      for (int j = 0; j < 4; j++) {
        int kk = qrow - (plocb + j) + 63;
        if (kk >= 0 && kk < 64) bsA[swz(qrow, kk)] = (f16)a2[j];
      }
    }
    // ---- p2c: 5-tile window [3-wid, 7-wid]; scatter into bs2[q][k] ----
#pragma unroll
    for (int t = 0; t < 5; t++) {
      int nb = 3 - wid + t;
      f32x4 a2 = {};
#pragma unroll
      for (int ks = 0; ks < 2; ks++) {
        f16x8 bq_ = *(const f16x8*)&Bpq[swz(nb * 16 + l16, ks * 32 + g4 * 8)];
        a2 = mfma16(kfw[ks], bq_, a2);
      }
#pragma unroll
      for (int j = 0; j < 4; j++) {
        int kk = wid * 16 + g4 * 4 + j;
        int qq = nb * 16 + l16 + kk - 63;
        if (qq >= 0 && qq < 64) bs2[swz(qq, kk)] = (f16)a2[j];
      }
    }
    if (kb < 7) issueK(kb + 1);  // kf/kfw consumed; ~2K-cycle gap to next use
    __syncthreads();  // S2: scatters visible; band LDS reads done
    if (kb < 7) issueBands(kb + 1);  // async into band LDS; drained at next S1

    // ---- softmax (log2 domain, defer-max): aligned vector reads only ----
    f16x4 pa4[4], pc4[4];
#pragma unroll
    for (int ni = 0; ni < 4; ni++) {
      int kb4 = ni * 16 + g4 * 4;
      pa4[ni] = *(const f16x4*)&bsA[swz(qrow, kb4)];
      pc4[ni] = *(const f16x4*)&bs2[swz(qrow, kb4)];
    }
    float mt = -1e30f;
#pragma unroll
    for (int ni = 0; ni < 4; ni++)
#pragma unroll
      for (int j = 0; j < 4; j++) {
        float v = (sc[ni][j] + (float)pa4[ni][j] + (float)pc4[ni][j]) * scale2;
        sc[ni][j] = v;
        mt = fmaxf(mt, v);
      }
    if (!__all(mt <= mx + 6.0f)) {  // slow path: true row max + rescale
      float m2 = fmaxf(mt, __shfl_xor(mt, 16, 64));
      m2 = fmaxf(m2, __shfl_xor(m2, 32, 64));
      float corr = __builtin_amdgcn_exp2f(mx - m2);
      mx = m2;
      lpart *= corr;
#pragma unroll
      for (int mi = 0; mi < 4; mi++) ctx[mi] *= corr;
    }
    float rs = 0.f;
#pragma unroll
    for (int ni = 0; ni < 4; ni++) {
      float p0 = __builtin_amdgcn_exp2f(sc[ni][0] - mx);
      float p1 = __builtin_amdgcn_exp2f(sc[ni][1] - mx);
      float p2 = __builtin_amdgcn_exp2f(sc[ni][2] - mx);
      float p3 = __builtin_amdgcn_exp2f(sc[ni][3] - mx);
      rs += (p0 + p1) + (p2 + p3);
      *(f16x4*)&bsA[swz(qrow, ni * 16 + g4 * 4)] = pack4(p0, p1, p2, p3);  // P, own row
    }
    lpart += rs;  // lane-partial; cross-lane reduce at epilogue

    // ---- PV^T: ctx[d][q] += V^T[d][k] * P^T[k][q] (all operands in regs) ----
    f16x8 pa[2];
#pragma unroll
    for (int ks = 0; ks < 2; ks++) pa[ks] = *(const f16x8*)&bsA[swz(qrow, ks * 32 + g4 * 8)];
#pragma unroll
    for (int mi = 0; mi < 4; mi++)
#pragma unroll
      for (int ks = 0; ks < 2; ks++) ctx[mi] = mfma16(vf[ks][mi], pa[ks], ctx[mi]);
    if (kb < 7) issueV(kb + 1);  // vf consumed
  }
  // epilogue: reduce lane-partial lsum over g4 group, store float4
  float ls = lpart;
  ls += __shfl_xor(ls, 16, 64);
  ls += __shfl_xor(ls, 32, 64);
  float inv_l = 1.0f / ls;
#pragma unroll
  for (int mi = 0; mi < 4; mi++) {
    float4 o;
    o.x = ctx[mi][0] * inv_l;
    o.y = ctx[mi][1] * inv_l;
    o.z = ctx[mi][2] * inv_l;
    o.w = ctx[mi][3] * inv_l;
    *(float4*)&out[(b * 512 + q0 + qrow) * 768 + h * 64 + mi * 16 + g4 * 4] = o;
  }
}

extern "C" void kernel_launch(void* const* d_in, const int* in_sizes, int n_in,
                              void* d_out, int out_size, void* d_ws, size_t ws_size,
                              hipStream_t stream) {
  const float* q = (const float*)d_in[0];
  const float* k = (const float*)d_in[1];
  const float* v = (const float*)d_in[2];
  const float* rel = (const float*)d_in[3];
  const float* Wq = (const float*)d_in[4];
  const float* bq = (const float*)d_in[5];
  const float* Wk = (const float*)d_in[6];
  const float* bk = (const float*)d_in[7];
  const float* Wv = (const float*)d_in[8];
  const float* bv = (const float*)d_in[9];
  float* out = (float*)d_out;

  f16* ws = (f16*)d_ws;
  f16* Wtq = ws;
  f16* Wtk = Wtq + 589824;
  f16* Wtv = Wtk + 589824;
  f16* Qh = Wtv + 589824;
  f16* Kh = Qh + 6291456;
  f16* VhT = Kh + 6291456;
  f16* pk = VhT + 6291456;
  f16* pq = pk + 786432;

  wtk3<<<dim3(24, 24, 3), dim3(32, 8), 0, stream>>>(Wq, Wk, Wv, Wtq, Wtk, Wtv);
  gemm_fused<<<dim3(64, 6, 3), 256, 0, stream>>>(q, k, v, Wtq, Wtk, Wtv,
                                                 bq, bk, bv, Qh, Kh, VhT, 0);
  gemm_fused<<<dim3(8, 6, 2), 256, 0, stream>>>(rel, rel, rel, Wtq, Wtk, Wtv,
                                                bq, bk, bv, pk, pq, pq, 1);
  attn<<<dim3(1536), 256, 0, stream>>>(Qh, Kh, VhT, pk, pq, out);
}

// Round 7
// 192.079 us; speedup vs baseline: 1.7017x; 1.1655x over previous
//
#include <hip/hip_runtime.h>

// DeBERTa disentangled attention, MI355X fp16-MFMA. R7:
// - attn: R5 structure (reg-prefetch -> LDS commit for K/V/bands, 64KB LDS,
//   2 barriers, 5-tile band windows, setprio), with issue() moved to after
//   S2 (loads cross no barrier before commit -> no vmcnt-drain exposure),
//   defer-max softmax (THR=6, log2 domain), lane-partial lsum.
// - projections: R6 fused wtk3 / qkv GEMM (z=3) / pos GEMM (z=2) with
//   A-reg-prefetch + async gll16 B staging (proven -27.5us).

typedef _Float16 f16;
typedef f16 f16x4 __attribute__((ext_vector_type(4)));
typedef f16 f16x8 __attribute__((ext_vector_type(8)));
typedef __fp16 fp16x2 __attribute__((ext_vector_type(2)));
typedef float f32x4 __attribute__((ext_vector_type(4)));

#define D_ 768

__device__ __forceinline__ int swz(int r, int c) { return r * 64 + (c ^ ((r & 7) << 3)); }

__device__ __forceinline__ f32x4 mfma16(f16x8 a, f16x8 b, f32x4 c) {
  return __builtin_amdgcn_mfma_f32_16x16x32_f16(a, b, c, 0, 0, 0);
}

__device__ __forceinline__ f16x4 pack4(float a, float b, float c, float d) {
  fp16x2 lo = __builtin_amdgcn_cvt_pkrtz(a, b);
  fp16x2 hi = __builtin_amdgcn_cvt_pkrtz(c, d);
  f16x4 r;
  r[0] = (f16)lo[0]; r[1] = (f16)lo[1]; r[2] = (f16)hi[0]; r[3] = (f16)hi[1];
  return r;
}

__device__ __forceinline__ void gll16(const f16* g, f16* l) {
  __builtin_amdgcn_global_load_lds((const __attribute__((address_space(1))) void*)g,
                                   (__attribute__((address_space(3))) void*)l, 16, 0, 0);
}

// ---------------- W transpose + cvt (z selects weight):  Wt[n][k] = (f16) W[k][n]
__global__ __launch_bounds__(256) void wtk3(const float* __restrict__ W0, const float* __restrict__ W1,
                                            const float* __restrict__ W2, f16* __restrict__ T0,
                                            f16* __restrict__ T1, f16* __restrict__ T2) {
  __shared__ float t[32][33];
  int z = blockIdx.z;
  const float* W = z == 0 ? W0 : z == 1 ? W1 : W2;
  f16* Wt = z == 0 ? T0 : z == 1 ? T1 : T2;
  int tx = threadIdx.x, ty = threadIdx.y;  // 32 x 8
  int k0 = blockIdx.x * 32, n0 = blockIdx.y * 32;
  for (int i = ty; i < 32; i += 8) t[i][tx] = W[(k0 + i) * D_ + n0 + tx];
  __syncthreads();
  for (int i = ty; i < 32; i += 8) Wt[(n0 + i) * D_ + k0 + tx] = (f16)t[tx][i];
}

// ---------------- fused projection GEMM: out16 = f16(A @ W + bias) ----------
// which==0 (grid z=3): z0 (q,Wtq,bq,Qh,m0) z1 (k,Wtk,bk,Kh,m0) z2 (v,Wtv,bv,VhT,m2)
// which==1 (grid z=2): z0 (rel,Wtk,bk,pk,m1) z1 (rel,Wtq,bq,pq,m1)
__global__ __launch_bounds__(256) void gemm_fused(
    const float* __restrict__ A0, const float* __restrict__ A1, const float* __restrict__ A2,
    const f16* __restrict__ W0, const f16* __restrict__ W1, const f16* __restrict__ W2,
    const float* __restrict__ b0, const float* __restrict__ b1, const float* __restrict__ b2,
    f16* __restrict__ o0, f16* __restrict__ o1, f16* __restrict__ o2, int which) {
  __shared__ f16 As[128 * 64];
  __shared__ f16 Bs[128 * 64];
  int z = blockIdx.z;
  const float* A; const f16* Wt; const float* bias; f16* out; int mode;
  if (which == 0) {
    A = z == 0 ? A0 : z == 1 ? A1 : A2;
    Wt = z == 0 ? W0 : z == 1 ? W1 : W2;
    bias = z == 0 ? b0 : z == 1 ? b1 : b2;
    out = z == 0 ? o0 : z == 1 ? o1 : o2;
    mode = z == 2 ? 2 : 0;
  } else {
    A = A0;
    Wt = z == 0 ? W1 : W0;
    bias = z == 0 ? b1 : b0;
    out = z == 0 ? o0 : o1;
    mode = 1;
  }
  int tid = threadIdx.x, lane = tid & 63, wid = tid >> 6;
  int g4 = lane >> 4, l16 = lane & 15;
  int m0 = blockIdx.x * 128, n0 = blockIdx.y * 128;
  int wr = wid >> 1, wc = wid & 1;
  f32x4 acc[4][4] = {};
  float4 pfA[8];

  auto issueA = [&](int k0) {
#pragma unroll
    for (int i = 0; i < 8; i++) {
      int s = tid + i * 256, r = s >> 4, c = (s & 15) * 4;
      pfA[i] = *(const float4*)(A + (m0 + r) * D_ + k0 + c);
    }
  };

  issueA(0);
  for (int kb = 0; kb < 12; kb++) {
    int k0 = kb * 64;
    __syncthreads();  // prev-iter LDS reads done
#pragma unroll
    for (int i = 0; i < 4; i++) {
      int s = tid + i * 256, r = s >> 3, c = (s & 7) * 8;
      int csw = c ^ ((r & 7) << 3);
      gll16(Wt + (n0 + r) * D_ + k0 + csw, &Bs[s * 8]);
    }
#pragma unroll
    for (int i = 0; i < 8; i++) {
      int s = tid + i * 256, r = s >> 4, c = (s & 15) * 4;
      float4 x = pfA[i];
      f16x4 hv; hv[0] = (f16)x.x; hv[1] = (f16)x.y; hv[2] = (f16)x.z; hv[3] = (f16)x.w;
      *(f16x4*)&As[swz(r, c)] = hv;
    }
    if (kb < 11) issueA(k0 + 64);
    __syncthreads();  // drains gll + ds_writes
#pragma unroll
    for (int ks = 0; ks < 2; ks++) {
      f16x8 af[4], bf[4];
#pragma unroll
      for (int mi = 0; mi < 4; mi++) af[mi] = *(const f16x8*)&As[swz(wr * 64 + mi * 16 + l16, ks * 32 + g4 * 8)];
#pragma unroll
      for (int ni = 0; ni < 4; ni++) bf[ni] = *(const f16x8*)&Bs[swz(wc * 64 + ni * 16 + l16, ks * 32 + g4 * 8)];
#pragma unroll
      for (int mi = 0; mi < 4; mi++)
#pragma unroll
        for (int ni = 0; ni < 4; ni++) acc[mi][ni] = mfma16(af[mi], bf[ni], acc[mi][ni]);
    }
  }
#pragma unroll
  for (int mi = 0; mi < 4; mi++)
#pragma unroll
    for (int ni = 0; ni < 4; ni++) {
      int mb = m0 + wr * 64 + mi * 16 + g4 * 4;  // j=0 row
      int n = n0 + wc * 64 + ni * 16 + l16;
      int h = n >> 6, hd = n & 63;
      if (mode == 2) {
        int b = mb >> 9, s = mb & 511;
        f16x4 hv;
#pragma unroll
        for (int j = 0; j < 4; j++) hv[j] = (f16)(acc[mi][ni][j] + bias[n]);
        *(f16x4*)&out[(((b * 12 + h) * 64) + hd) * 512 + s] = hv;
      } else {
#pragma unroll
        for (int j = 0; j < 4; j++) {
          int m = mb + j;
          float v = acc[mi][ni][j] + bias[n];
          int idx;
          if (mode == 0) {
            int b = m >> 9, s = m & 511;
            idx = (((b * 12 + h) * 512) + s) * 64 + hd;
          } else {
            idx = ((h * 1024) + m) * 64 + hd;
          }
          out[idx] = (f16)v;
        }
      }
    }
}

// ---------------- fused disentangled attention ----------------
// flat grid 1536 blocks (XCD-swizzled), 256 threads (4 waves). QBLK=KBLK=64.
// Lane owns q-row qrow; scores S^T[k][q] via mfma(K,Q).
__global__ __launch_bounds__(256, 2) void attn(const f16* __restrict__ Qh, const f16* __restrict__ Kh,
                                               const f16* __restrict__ VhT, const f16* __restrict__ posk,
                                               const f16* __restrict__ posq, float* __restrict__ out) {
  __shared__ f16 Ks_[64 * 64];   // 8 KB  [k][d]
  __shared__ f16 Vts[64 * 64];   // 8 KB  [d][k]
  __shared__ f16 Bcp[128 * 64];  // 16 KB posk band rows [r][d]
  __shared__ f16 Bpq[128 * 64];  // 16 KB posq band rows [r][d]
  __shared__ f16 bsA[64 * 64];   // 8 KB  c2p gathered [q][k]; P[q][k] after softmax
  __shared__ f16 bs2[64 * 64];   // 8 KB  p2c gathered [q][k]

  int tid = threadIdx.x, lane = tid & 63, wid = tid >> 6;
  int g4 = lane >> 4, l16 = lane & 15;
  // bijective XCD swizzle (1536 % 8 == 0)
  int flat = blockIdx.x;
  int work = (flat & 7) * 192 + (flat >> 3);
  int q0 = (work & 7) * 64;
  int hb = work >> 3;
  int h = hb % 12, b = hb / 12;

  const f16* Qg = Qh + (b * 12 + h) * 512 * 64;
  const f16* Kg = Kh + (b * 12 + h) * 512 * 64;
  const f16* Vg = VhT + (b * 12 + h) * 64 * 512;  // [d][s]
  const f16* PKg = posk + h * 1024 * 64;
  const f16* PQg = posq + h * 1024 * 64;

  int qrow = wid * 16 + l16;  // lane's local q
  f16x8 qf[2];
#pragma unroll
  for (int ks = 0; ks < 2; ks++) qf[ks] = *(const f16x8*)(Qg + (q0 + qrow) * 64 + ks * 32 + g4 * 8);

  // prefetch registers
  f16x8 pfK[2], pfV[2], pfC[4], pfP[4];

  auto issue = [&](int kb) {
    int k0 = kb * 64, pbase = q0 - k0 + 449;
#pragma unroll
    for (int i = 0; i < 2; i++) {
      int s = tid + i * 256, r = s >> 3, c = (s & 7) * 8;
      pfK[i] = *(const f16x8*)(Kg + (k0 + r) * 64 + c);
      pfV[i] = *(const f16x8*)(Vg + r * 512 + k0 + c);
    }
#pragma unroll
    for (int i = 0; i < 4; i++) {
      int s = tid + i * 256, r = s >> 3, c = (s & 7) * 8;
      int prow = pbase + r;
      prow = prow > 1023 ? 1023 : prow;
      pfC[i] = *(const f16x8*)(PKg + prow * 64 + c);
      pfP[i] = *(const f16x8*)(PQg + prow * 64 + c);
    }
  };
  auto commit = [&]() {
#pragma unroll
    for (int i = 0; i < 2; i++) {
      int s = tid + i * 256, r = s >> 3, c = (s & 7) * 8;
      *(f16x8*)&Ks_[swz(r, c)] = pfK[i];
      *(f16x8*)&Vts[swz(r, c)] = pfV[i];
    }
#pragma unroll
    for (int i = 0; i < 4; i++) {
      int s = tid + i * 256, r = s >> 3, c = (s & 7) * 8;
      *(f16x8*)&Bcp[swz(r, c)] = pfC[i];
      *(f16x8*)&Bpq[swz(r, c)] = pfP[i];
    }
  };

  float mx = -1e30f, lpart = 0.f;
  f32x4 ctx[4] = {};  // ctx^T: d = mi*16+g4*4+j, q = qrow
  const float scale2 = 0.07216878364870323f * 1.4426950408889634f;  // 1/sqrt(192)*log2e

  issue(0);
  for (int kb = 0; kb < 8; kb++) {
    commit();         // waits prefetch, writes LDS
    __syncthreads();  // S1: LDS ready; prev softmax reads of bsA/bs2 done

    // ---- fragment reads (ALL staged-LDS reads happen before S2) ----
    f16x8 kfw[2], kf[2][4], vf[2][4];
#pragma unroll
    for (int ks = 0; ks < 2; ks++) {
      kfw[ks] = *(const f16x8*)&Ks_[swz(qrow, ks * 32 + g4 * 8)];
#pragma unroll
      for (int ni = 0; ni < 4; ni++) {
        kf[ks][ni] = *(const f16x8*)&Ks_[swz(ni * 16 + l16, ks * 32 + g4 * 8)];
        vf[ks][ni] = *(const f16x8*)&Vts[swz(ni * 16 + l16, ks * 32 + g4 * 8)];
      }
    }
    __builtin_amdgcn_s_setprio(1);
    // ---- c2c^T: sc[ni] rows k=ni*16+g4*4+j, col q=qrow ----
    f32x4 sc[4] = {};
#pragma unroll
    for (int ks = 0; ks < 2; ks++)
#pragma unroll
      for (int ni = 0; ni < 4; ni++) sc[ni] = mfma16(kf[ks][ni], qf[ks], sc[ni]);

    // ---- c2p: 5-tile window [wid, wid+4]; scatter into bsA[qrow][k] ----
#pragma unroll
    for (int t = 0; t < 5; t++) {
      int mi = wid + t;
      f32x4 a2 = {};
#pragma unroll
      for (int ks = 0; ks < 2; ks++) {
        f16x8 bp = *(const f16x8*)&Bcp[swz(mi * 16 + l16, ks * 32 + g4 * 8)];
        a2 = mfma16(bp, qf[ks], a2);
      }
      int plocb = mi * 16 + g4 * 4;
#pragma unroll
      for (int j = 0; j < 4; j++) {
        int kk = qrow - (plocb + j) + 63;
        if (kk >= 0 && kk < 64) bsA[swz(qrow, kk)] = (f16)a2[j];
      }
    }
    // ---- p2c: 5-tile window [3-wid, 7-wid]; scatter into bs2[q][k] ----
#pragma unroll
    for (int t = 0; t < 5; t++) {
      int nb = 3 - wid + t;
      f32x4 a2 = {};
#pragma unroll
      for (int ks = 0; ks < 2; ks++) {
        f16x8 bq_ = *(const f16x8*)&Bpq[swz(nb * 16 + l16, ks * 32 + g4 * 8)];
        a2 = mfma16(kfw[ks], bq_, a2);
      }
#pragma unroll
      for (int j = 0; j < 4; j++) {
        int kk = wid * 16 + g4 * 4 + j;
        int qq = nb * 16 + l16 + kk - 63;
        if (qq >= 0 && qq < 64) bs2[swz(qq, kk)] = (f16)a2[j];
      }
    }
    __builtin_amdgcn_s_setprio(0);
    __syncthreads();  // S2: scatters visible; staged-LDS reads all done
    if (kb < 7) issue(kb + 1);  // loads cross NO barrier before commit()

    // ---- softmax (log2 domain, defer-max): aligned vector reads only ----
    f16x4 pa4[4], pc4[4];
#pragma unroll
    for (int ni = 0; ni < 4; ni++) {
      int kb4 = ni * 16 + g4 * 4;
      pa4[ni] = *(const f16x4*)&bsA[swz(qrow, kb4)];
      pc4[ni] = *(const f16x4*)&bs2[swz(qrow, kb4)];
    }
    float mt = -1e30f;
#pragma unroll
    for (int ni = 0; ni < 4; ni++)
#pragma unroll
      for (int j = 0; j < 4; j++) {
        float v = (sc[ni][j] + (float)pa4[ni][j] + (float)pc4[ni][j]) * scale2;
        sc[ni][j] = v;
        mt = fmaxf(mt, v);
      }
    if (!__all(mt <= mx + 6.0f)) {  // slow path: true row max + rescale
      float m2 = fmaxf(mt, __shfl_xor(mt, 16, 64));
      m2 = fmaxf(m2, __shfl_xor(m2, 32, 64));
      float corr = __builtin_amdgcn_exp2f(mx - m2);
      mx = m2;
      lpart *= corr;
#pragma unroll
      for (int mi = 0; mi < 4; mi++) ctx[mi] *= corr;
    }
    float rs = 0.f;
#pragma unroll
    for (int ni = 0; ni < 4; ni++) {
      float p0 = __builtin_amdgcn_exp2f(sc[ni][0] - mx);
      float p1 = __builtin_amdgcn_exp2f(sc[ni][1] - mx);
      float p2 = __builtin_amdgcn_exp2f(sc[ni][2] - mx);
      float p3 = __builtin_amdgcn_exp2f(sc[ni][3] - mx);
      rs += (p0 + p1) + (p2 + p3);
      *(f16x4*)&bsA[swz(qrow, ni * 16 + g4 * 4)] = pack4(p0, p1, p2, p3);  // P, own row
    }
    lpart += rs;  // lane-partial; cross-lane reduce at epilogue

    // ---- PV^T: ctx[d][q] += V^T[d][k] * P^T[k][q] (P read intra-wave) ----
    f16x8 pa[2];
#pragma unroll
    for (int ks = 0; ks < 2; ks++) pa[ks] = *(const f16x8*)&bsA[swz(qrow, ks * 32 + g4 * 8)];
    __builtin_amdgcn_s_setprio(1);
#pragma unroll
    for (int mi = 0; mi < 4; mi++)
#pragma unroll
      for (int ks = 0; ks < 2; ks++) ctx[mi] = mfma16(vf[ks][mi], pa[ks], ctx[mi]);
    __builtin_amdgcn_s_setprio(0);
    // no trailing barrier: next S1 protects bsA/bs2; staged reads done by S2
  }
  // epilogue: reduce lane-partial lsum over the l16 column group
  float ls = lpart;
  ls += __shfl_xor(ls, 16, 64);
  ls += __shfl_xor(ls, 32, 64);
  float inv_l = 1.0f / ls;
#pragma unroll
  for (int mi = 0; mi < 4; mi++) {
    float4 o;
    o.x = ctx[mi][0] * inv_l;
    o.y = ctx[mi][1] * inv_l;
    o.z = ctx[mi][2] * inv_l;
    o.w = ctx[mi][3] * inv_l;
    *(float4*)&out[(b * 512 + q0 + qrow) * 768 + h * 64 + mi * 16 + g4 * 4] = o;
  }
}

extern "C" void kernel_launch(void* const* d_in, const int* in_sizes, int n_in,
                              void* d_out, int out_size, void* d_ws, size_t ws_size,
                              hipStream_t stream) {
  const float* q = (const float*)d_in[0];
  const float* k = (const float*)d_in[1];
  const float* v = (const float*)d_in[2];
  const float* rel = (const float*)d_in[3];
  const float* Wq = (const float*)d_in[4];
  const float* bq = (const float*)d_in[5];
  const float* Wk = (const float*)d_in[6];
  const float* bk = (const float*)d_in[7];
  const float* Wv = (const float*)d_in[8];
  const float* bv = (const float*)d_in[9];
  float* out = (float*)d_out;

  f16* ws = (f16*)d_ws;
  f16* Wtq = ws;
  f16* Wtk = Wtq + 589824;
  f16* Wtv = Wtk + 589824;
  f16* Qh = Wtv + 589824;
  f16* Kh = Qh + 6291456;
  f16* VhT = Kh + 6291456;
  f16* pk = VhT + 6291456;
  f16* pq = pk + 786432;

  wtk3<<<dim3(24, 24, 3), dim3(32, 8), 0, stream>>>(Wq, Wk, Wv, Wtq, Wtk, Wtv);
  gemm_fused<<<dim3(64, 6, 3), 256, 0, stream>>>(q, k, v, Wtq, Wtk, Wtv,
                                                 bq, bk, bv, Qh, Kh, VhT, 0);
  gemm_fused<<<dim3(8, 6, 2), 256, 0, stream>>>(rel, rel, rel, Wtq, Wtk, Wtv,
                                                bq, bk, bv, pk, pq, pq, 1);
  attn<<<dim3(1536), 256, 0, stream>>>(Qh, Kh, VhT, pk, pq, out);
}

// Round 9
// 176.031 us; speedup vs baseline: 1.8569x; 1.0912x over previous
//
#include <hip/hip_runtime.h>

// DeBERTa disentangled attention, MI355X fp16-MFMA. R9:
// - attn: EXACT R7 kernel (proven 111.9us, passed post-timing validation):
//   reg-prefetch -> LDS commit for K/V/bands, 64KB LDS, launch_bounds(256,2),
//   issue() after S2, 5-tile band windows, defer-max softmax, lane-partial
//   lsum, setprio. R8's direct-global K/V + (256,3) diverged post-timing
//   (suspect: VGPR spill around barriers) - reverted.
// - projections: fused wtk3 (z=3) + single gemm_all launch (z=5).

typedef _Float16 f16;
typedef f16 f16x4 __attribute__((ext_vector_type(4)));
typedef f16 f16x8 __attribute__((ext_vector_type(8)));
typedef __fp16 fp16x2 __attribute__((ext_vector_type(2)));
typedef float f32x4 __attribute__((ext_vector_type(4)));

#define D_ 768

__device__ __forceinline__ int swz(int r, int c) { return r * 64 + (c ^ ((r & 7) << 3)); }

__device__ __forceinline__ f32x4 mfma16(f16x8 a, f16x8 b, f32x4 c) {
  return __builtin_amdgcn_mfma_f32_16x16x32_f16(a, b, c, 0, 0, 0);
}

__device__ __forceinline__ f16x4 pack4(float a, float b, float c, float d) {
  fp16x2 lo = __builtin_amdgcn_cvt_pkrtz(a, b);
  fp16x2 hi = __builtin_amdgcn_cvt_pkrtz(c, d);
  f16x4 r;
  r[0] = (f16)lo[0]; r[1] = (f16)lo[1]; r[2] = (f16)hi[0]; r[3] = (f16)hi[1];
  return r;
}

__device__ __forceinline__ void gll16(const f16* g, f16* l) {
  __builtin_amdgcn_global_load_lds((const __attribute__((address_space(1))) void*)g,
                                   (__attribute__((address_space(3))) void*)l, 16, 0, 0);
}

// ---------------- W transpose + cvt (z selects weight):  Wt[n][k] = (f16) W[k][n]
__global__ __launch_bounds__(256) void wtk3(const float* __restrict__ W0, const float* __restrict__ W1,
                                            const float* __restrict__ W2, f16* __restrict__ T0,
                                            f16* __restrict__ T1, f16* __restrict__ T2) {
  __shared__ float t[32][33];
  int z = blockIdx.z;
  const float* W = z == 0 ? W0 : z == 1 ? W1 : W2;
  f16* Wt = z == 0 ? T0 : z == 1 ? T1 : T2;
  int tx = threadIdx.x, ty = threadIdx.y;  // 32 x 8
  int k0 = blockIdx.x * 32, n0 = blockIdx.y * 32;
  for (int i = ty; i < 32; i += 8) t[i][tx] = W[(k0 + i) * D_ + n0 + tx];
  __syncthreads();
  for (int i = ty; i < 32; i += 8) Wt[(n0 + i) * D_ + k0 + tx] = (f16)t[tx][i];
}

// ---------------- fused projection GEMM, one launch (grid z=5) --------------
// z0 (q,Wtq,bq,Qh,mode0) z1 (k,Wtk,bk,Kh,mode0) z2 (v,Wtv,bv,VhT,mode2)
// z3 (rel,Wtk,bk,pk,mode1,x<8) z4 (rel,Wtq,bq,pq,mode1,x<8)
__global__ __launch_bounds__(256) void gemm_all(
    const float* __restrict__ Aq, const float* __restrict__ Ak, const float* __restrict__ Av,
    const float* __restrict__ rel,
    const f16* __restrict__ Wtq, const f16* __restrict__ Wtk, const f16* __restrict__ Wtv,
    const float* __restrict__ bq, const float* __restrict__ bk, const float* __restrict__ bv,
    f16* __restrict__ Qh, f16* __restrict__ Kh, f16* __restrict__ VhT,
    f16* __restrict__ pk, f16* __restrict__ pq) {
  int z = blockIdx.z;
  if (z >= 3 && blockIdx.x >= 8) return;  // pos tables: M=1024 only
  __shared__ f16 As[128 * 64];
  __shared__ f16 Bs[128 * 64];
  const float* A; const f16* Wt; const float* bias; f16* out; int mode;
  switch (z) {
    case 0: A = Aq; Wt = Wtq; bias = bq; out = Qh; mode = 0; break;
    case 1: A = Ak; Wt = Wtk; bias = bk; out = Kh; mode = 0; break;
    case 2: A = Av; Wt = Wtv; bias = bv; out = VhT; mode = 2; break;
    case 3: A = rel; Wt = Wtk; bias = bk; out = pk; mode = 1; break;
    default: A = rel; Wt = Wtq; bias = bq; out = pq; mode = 1; break;
  }
  int tid = threadIdx.x, lane = tid & 63, wid = tid >> 6;
  int g4 = lane >> 4, l16 = lane & 15;
  int m0 = blockIdx.x * 128, n0 = blockIdx.y * 128;
  int wr = wid >> 1, wc = wid & 1;
  f32x4 acc[4][4] = {};
  float4 pfA[8];

  auto issueA = [&](int k0) {
#pragma unroll
    for (int i = 0; i < 8; i++) {
      int s = tid + i * 256, r = s >> 4, c = (s & 15) * 4;
      pfA[i] = *(const float4*)(A + (m0 + r) * D_ + k0 + c);
    }
  };

  issueA(0);
  for (int kb = 0; kb < 12; kb++) {
    int k0 = kb * 64;
    __syncthreads();  // prev-iter LDS reads done
#pragma unroll
    for (int i = 0; i < 4; i++) {
      int s = tid + i * 256, r = s >> 3, c = (s & 7) * 8;
      int csw = c ^ ((r & 7) << 3);
      gll16(Wt + (n0 + r) * D_ + k0 + csw, &Bs[s * 8]);
    }
#pragma unroll
    for (int i = 0; i < 8; i++) {
      int s = tid + i * 256, r = s >> 4, c = (s & 15) * 4;
      float4 x = pfA[i];
      f16x4 hv; hv[0] = (f16)x.x; hv[1] = (f16)x.y; hv[2] = (f16)x.z; hv[3] = (f16)x.w;
      *(f16x4*)&As[swz(r, c)] = hv;
    }
    if (kb < 11) issueA(k0 + 64);
    __syncthreads();  // drains gll + ds_writes
#pragma unroll
    for (int ks = 0; ks < 2; ks++) {
      f16x8 af[4], bf[4];
#pragma unroll
      for (int mi = 0; mi < 4; mi++) af[mi] = *(const f16x8*)&As[swz(wr * 64 + mi * 16 + l16, ks * 32 + g4 * 8)];
#pragma unroll
      for (int ni = 0; ni < 4; ni++) bf[ni] = *(const f16x8*)&Bs[swz(wc * 64 + ni * 16 + l16, ks * 32 + g4 * 8)];
#pragma unroll
      for (int mi = 0; mi < 4; mi++)
#pragma unroll
        for (int ni = 0; ni < 4; ni++) acc[mi][ni] = mfma16(af[mi], bf[ni], acc[mi][ni]);
    }
  }
#pragma unroll
  for (int mi = 0; mi < 4; mi++)
#pragma unroll
    for (int ni = 0; ni < 4; ni++) {
      int mb = m0 + wr * 64 + mi * 16 + g4 * 4;  // j=0 row
      int n = n0 + wc * 64 + ni * 16 + l16;
      int h = n >> 6, hd = n & 63;
      if (mode == 2) {
        int b = mb >> 9, s = mb & 511;
        f16x4 hv;
#pragma unroll
        for (int j = 0; j < 4; j++) hv[j] = (f16)(acc[mi][ni][j] + bias[n]);
        *(f16x4*)&out[(((b * 12 + h) * 64) + hd) * 512 + s] = hv;
      } else {
#pragma unroll
        for (int j = 0; j < 4; j++) {
          int m = mb + j;
          float v = acc[mi][ni][j] + bias[n];
          int idx;
          if (mode == 0) {
            int b = m >> 9, s = m & 511;
            idx = (((b * 12 + h) * 512) + s) * 64 + hd;
          } else {
            idx = ((h * 1024) + m) * 64 + hd;
          }
          out[idx] = (f16)v;
        }
      }
    }
}

// ---------------- fused disentangled attention (R7 verbatim) ----------------
// flat grid 1536 blocks (XCD-swizzled), 256 threads (4 waves). QBLK=KBLK=64.
// Lane owns q-row qrow; scores S^T[k][q] via mfma(K,Q).
__global__ __launch_bounds__(256, 2) void attn(const f16* __restrict__ Qh, const f16* __restrict__ Kh,
                                               const f16* __restrict__ VhT, const f16* __restrict__ posk,
                                               const f16* __restrict__ posq, float* __restrict__ out) {
  __shared__ f16 Ks_[64 * 64];   // 8 KB  [k][d]
  __shared__ f16 Vts[64 * 64];   // 8 KB  [d][k]
  __shared__ f16 Bcp[128 * 64];  // 16 KB posk band rows [r][d]
  __shared__ f16 Bpq[128 * 64];  // 16 KB posq band rows [r][d]
  __shared__ f16 bsA[64 * 64];   // 8 KB  c2p gathered [q][k]; P[q][k] after softmax
  __shared__ f16 bs2[64 * 64];   // 8 KB  p2c gathered [q][k]

  int tid = threadIdx.x, lane = tid & 63, wid = tid >> 6;
  int g4 = lane >> 4, l16 = lane & 15;
  // bijective XCD swizzle (1536 % 8 == 0)
  int flat = blockIdx.x;
  int work = (flat & 7) * 192 + (flat >> 3);
  int q0 = (work & 7) * 64;
  int hb = work >> 3;
  int h = hb % 12, b = hb / 12;

  const f16* Qg = Qh + (b * 12 + h) * 512 * 64;
  const f16* Kg = Kh + (b * 12 + h) * 512 * 64;
  const f16* Vg = VhT + (b * 12 + h) * 64 * 512;  // [d][s]
  const f16* PKg = posk + h * 1024 * 64;
  const f16* PQg = posq + h * 1024 * 64;

  int qrow = wid * 16 + l16;  // lane's local q
  f16x8 qf[2];
#pragma unroll
  for (int ks = 0; ks < 2; ks++) qf[ks] = *(const f16x8*)(Qg + (q0 + qrow) * 64 + ks * 32 + g4 * 8);

  // prefetch registers
  f16x8 pfK[2], pfV[2], pfC[4], pfP[4];

  auto issue = [&](int kb) {
    int k0 = kb * 64, pbase = q0 - k0 + 449;
#pragma unroll
    for (int i = 0; i < 2; i++) {
      int s = tid + i * 256, r = s >> 3, c = (s & 7) * 8;
      pfK[i] = *(const f16x8*)(Kg + (k0 + r) * 64 + c);
      pfV[i] = *(const f16x8*)(Vg + r * 512 + k0 + c);
    }
#pragma unroll
    for (int i = 0; i < 4; i++) {
      int s = tid + i * 256, r = s >> 3, c = (s & 7) * 8;
      int prow = pbase + r;
      prow = prow > 1023 ? 1023 : prow;
      pfC[i] = *(const f16x8*)(PKg + prow * 64 + c);
      pfP[i] = *(const f16x8*)(PQg + prow * 64 + c);
    }
  };
  auto commit = [&]() {
#pragma unroll
    for (int i = 0; i < 2; i++) {
      int s = tid + i * 256, r = s >> 3, c = (s & 7) * 8;
      *(f16x8*)&Ks_[swz(r, c)] = pfK[i];
      *(f16x8*)&Vts[swz(r, c)] = pfV[i];
    }
#pragma unroll
    for (int i = 0; i < 4; i++) {
      int s = tid + i * 256, r = s >> 3, c = (s & 7) * 8;
      *(f16x8*)&Bcp[swz(r, c)] = pfC[i];
      *(f16x8*)&Bpq[swz(r, c)] = pfP[i];
    }
  };

  float mx = -1e30f, lpart = 0.f;
  f32x4 ctx[4] = {};  // ctx^T: d = mi*16+g4*4+j, q = qrow
  const float scale2 = 0.07216878364870323f * 1.4426950408889634f;  // 1/sqrt(192)*log2e

  issue(0);
  for (int kb = 0; kb < 8; kb++) {
    commit();         // waits prefetch, writes LDS
    __syncthreads();  // S1: LDS ready; prev softmax reads of bsA/bs2 done

    // ---- fragment reads (ALL staged-LDS reads happen before S2) ----
    f16x8 kfw[2], kf[2][4], vf[2][4];
#pragma unroll
    for (int ks = 0; ks < 2; ks++) {
      kfw[ks] = *(const f16x8*)&Ks_[swz(qrow, ks * 32 + g4 * 8)];
#pragma unroll
      for (int ni = 0; ni < 4; ni++) {
        kf[ks][ni] = *(const f16x8*)&Ks_[swz(ni * 16 + l16, ks * 32 + g4 * 8)];
        vf[ks][ni] = *(const f16x8*)&Vts[swz(ni * 16 + l16, ks * 32 + g4 * 8)];
      }
    }
    __builtin_amdgcn_s_setprio(1);
    // ---- c2c^T: sc[ni] rows k=ni*16+g4*4+j, col q=qrow ----
    f32x4 sc[4] = {};
#pragma unroll
    for (int ks = 0; ks < 2; ks++)
#pragma unroll
      for (int ni = 0; ni < 4; ni++) sc[ni] = mfma16(kf[ks][ni], qf[ks], sc[ni]);

    // ---- c2p: 5-tile window [wid, wid+4]; scatter into bsA[qrow][k] ----
#pragma unroll
    for (int t = 0; t < 5; t++) {
      int mi = wid + t;
      f32x4 a2 = {};
#pragma unroll
      for (int ks = 0; ks < 2; ks++) {
        f16x8 bp = *(const f16x8*)&Bcp[swz(mi * 16 + l16, ks * 32 + g4 * 8)];
        a2 = mfma16(bp, qf[ks], a2);
      }
      int plocb = mi * 16 + g4 * 4;
#pragma unroll
      for (int j = 0; j < 4; j++) {
        int kk = qrow - (plocb + j) + 63;
        if (kk >= 0 && kk < 64) bsA[swz(qrow, kk)] = (f16)a2[j];
      }
    }
    // ---- p2c: 5-tile window [3-wid, 7-wid]; scatter into bs2[q][k] ----
#pragma unroll
    for (int t = 0; t < 5; t++) {
      int nb = 3 - wid + t;
      f32x4 a2 = {};
#pragma unroll
      for (int ks = 0; ks < 2; ks++) {
        f16x8 bq_ = *(const f16x8*)&Bpq[swz(nb * 16 + l16, ks * 32 + g4 * 8)];
        a2 = mfma16(kfw[ks], bq_, a2);
      }
#pragma unroll
      for (int j = 0; j < 4; j++) {
        int kk = wid * 16 + g4 * 4 + j;
        int qq = nb * 16 + l16 + kk - 63;
        if (qq >= 0 && qq < 64) bs2[swz(qq, kk)] = (f16)a2[j];
      }
    }
    __builtin_amdgcn_s_setprio(0);
    __syncthreads();  // S2: scatters visible; staged-LDS reads all done
    if (kb < 7) issue(kb + 1);  // loads cross NO barrier before commit()

    // ---- softmax (log2 domain, defer-max): aligned vector reads only ----
    f16x4 pa4[4], pc4[4];
#pragma unroll
    for (int ni = 0; ni < 4; ni++) {
      int kb4 = ni * 16 + g4 * 4;
      pa4[ni] = *(const f16x4*)&bsA[swz(qrow, kb4)];
      pc4[ni] = *(const f16x4*)&bs2[swz(qrow, kb4)];
    }
    float mt = -1e30f;
#pragma unroll
    for (int ni = 0; ni < 4; ni++)
#pragma unroll
      for (int j = 0; j < 4; j++) {
        float v = (sc[ni][j] + (float)pa4[ni][j] + (float)pc4[ni][j]) * scale2;
        sc[ni][j] = v;
        mt = fmaxf(mt, v);
      }
    if (!__all(mt <= mx + 6.0f)) {  // slow path: true row max + rescale
      float m2 = fmaxf(mt, __shfl_xor(mt, 16, 64));
      m2 = fmaxf(m2, __shfl_xor(m2, 32, 64));
      float corr = __builtin_amdgcn_exp2f(mx - m2);
      mx = m2;
      lpart *= corr;
#pragma unroll
      for (int mi = 0; mi < 4; mi++) ctx[mi] *= corr;
    }
    float rs = 0.f;
#pragma unroll
    for (int ni = 0; ni < 4; ni++) {
      float p0 = __builtin_amdgcn_exp2f(sc[ni][0] - mx);
      float p1 = __builtin_amdgcn_exp2f(sc[ni][1] - mx);
      float p2 = __builtin_amdgcn_exp2f(sc[ni][2] - mx);
      float p3 = __builtin_amdgcn_exp2f(sc[ni][3] - mx);
      rs += (p0 + p1) + (p2 + p3);
      *(f16x4*)&bsA[swz(qrow, ni * 16 + g4 * 4)] = pack4(p0, p1, p2, p3);  // P, own row
    }
    lpart += rs;  // lane-partial; cross-lane reduce at epilogue

    // ---- PV^T: ctx[d][q] += V^T[d][k] * P^T[k][q] (P read intra-wave) ----
    f16x8 pa[2];
#pragma unroll
    for (int ks = 0; ks < 2; ks++) pa[ks] = *(const f16x8*)&bsA[swz(qrow, ks * 32 + g4 * 8)];
    __builtin_amdgcn_s_setprio(1);
#pragma unroll
    for (int mi = 0; mi < 4; mi++)
#pragma unroll
      for (int ks = 0; ks < 2; ks++) ctx[mi] = mfma16(vf[ks][mi], pa[ks], ctx[mi]);
    __builtin_amdgcn_s_setprio(0);
    // no trailing barrier: next S1 protects bsA/bs2; staged reads done by S2
  }
  // epilogue: reduce lane-partial lsum over the l16 column group
  float ls = lpart;
  ls += __shfl_xor(ls, 16, 64);
  ls += __shfl_xor(ls, 32, 64);
  float inv_l = 1.0f / ls;
#pragma unroll
  for (int mi = 0; mi < 4; mi++) {
    float4 o;
    o.x = ctx[mi][0] * inv_l;
    o.y = ctx[mi][1] * inv_l;
    o.z = ctx[mi][2] * inv_l;
    o.w = ctx[mi][3] * inv_l;
    *(float4*)&out[(b * 512 + q0 + qrow) * 768 + h * 64 + mi * 16 + g4 * 4] = o;
  }
}

extern "C" void kernel_launch(void* const* d_in, const int* in_sizes, int n_in,
                              void* d_out, int out_size, void* d_ws, size_t ws_size,
                              hipStream_t stream) {
  const float* q = (const float*)d_in[0];
  const float* k = (const float*)d_in[1];
  const float* v = (const float*)d_in[2];
  const float* rel = (const float*)d_in[3];
  const float* Wq = (const float*)d_in[4];
  const float* bq = (const float*)d_in[5];
  const float* Wk = (const float*)d_in[6];
  const float* bk = (const float*)d_in[7];
  const float* Wv = (const float*)d_in[8];
  const float* bv = (const float*)d_in[9];
  float* out = (float*)d_out;

  f16* ws = (f16*)d_ws;
  f16* Wtq = ws;
  f16* Wtk = Wtq + 589824;
  f16* Wtv = Wtk + 589824;
  f16* Qh = Wtv + 589824;
  f16* Kh = Qh + 6291456;
  f16* VhT = Kh + 6291456;
  f16* pk = VhT + 6291456;
  f16* pq = pk + 786432;

  wtk3<<<dim3(24, 24, 3), dim3(32, 8), 0, stream>>>(Wq, Wk, Wv, Wtq, Wtk, Wtv);
  gemm_all<<<dim3(64, 6, 5), 256, 0, stream>>>(q, k, v, rel, Wtq, Wtk, Wtv,
                                               bq, bk, bv, Qh, Kh, VhT, pk, pq);
  attn<<<dim3(1536), 256, 0, stream>>>(Qh, Kh, VhT, pk, pq, out);
}